// Round 3
// baseline (13828.239 us; speedup 1.0000x reference)
//
#include <hip/hip_runtime.h>
#include <math.h>
#include <stddef.h>

static constexpr int B_   = 256;
static constexpr int N_   = 64;
static constexpr int D_   = 256;
static constexpr int DH_  = 32;
static constexpr int L_   = 18;
static constexpr int RM   = B_ * N_;      // 16384 rows per stream
static constexpr int RM2  = 2 * RM;       // 32768 rows (both streams)

// ---------------------------------------------------------------------------
// GEMM: C[M,N] = act(A[M,K] @ W[K,N] + bias).  64x64 tile, 4x4 per thread,
// BK=32, A staged transposed in LDS so fragment reads are ds_read_b128.
// If A2 != nullptr: K==512, logical A = [A1 | A2] each M x 256 (concat mode).
// ---------------------------------------------------------------------------
__global__ __launch_bounds__(256)
void gemm_kernel(const float* __restrict__ A, const float* __restrict__ A2,
                 const float* __restrict__ W, const float* __restrict__ bias,
                 float* __restrict__ C, int M, int N, int K, int relu)
{
    __shared__ float As[32][64];
    __shared__ float Ws[32][64];
    const int tid  = threadIdx.x;
    const int tx   = tid & 15, ty = tid >> 4;
    const int row0 = blockIdx.x * 64;
    const int col0 = blockIdx.y * 64;

    const int lrow = tid >> 2;          // 0..63
    const int lk4  = (tid & 3) * 4;     // 0,4,8,12
    const int wk   = tid >> 4;          // 0..15
    const int wc   = (tid & 15) * 4;    // 0..60

    float acc[4][4] = {{0.f,0.f,0.f,0.f},{0.f,0.f,0.f,0.f},
                       {0.f,0.f,0.f,0.f},{0.f,0.f,0.f,0.f}};

    for (int k0 = 0; k0 < K; k0 += 32) {
        const int kg0 = k0 + lk4, kg1 = k0 + lk4 + 16;
        float4 av0, av1, wv0, wv1;
        if (A2 == nullptr) {
            av0 = *(const float4*)&A[(size_t)(row0 + lrow) * K + kg0];
            av1 = *(const float4*)&A[(size_t)(row0 + lrow) * K + kg1];
        } else {
            const float* s0 = (kg0 < 256) ? &A [(size_t)(row0 + lrow) * 256 + kg0]
                                          : &A2[(size_t)(row0 + lrow) * 256 + (kg0 - 256)];
            const float* s1 = (kg1 < 256) ? &A [(size_t)(row0 + lrow) * 256 + kg1]
                                          : &A2[(size_t)(row0 + lrow) * 256 + (kg1 - 256)];
            av0 = *(const float4*)s0;
            av1 = *(const float4*)s1;
        }
        wv0 = *(const float4*)&W[(size_t)(k0 + wk)      * N + col0 + wc];
        wv1 = *(const float4*)&W[(size_t)(k0 + wk + 16) * N + col0 + wc];
        __syncthreads();
        As[lk4 + 0][lrow] = av0.x; As[lk4 + 1][lrow] = av0.y;
        As[lk4 + 2][lrow] = av0.z; As[lk4 + 3][lrow] = av0.w;
        As[lk4 + 16][lrow] = av1.x; As[lk4 + 17][lrow] = av1.y;
        As[lk4 + 18][lrow] = av1.z; As[lk4 + 19][lrow] = av1.w;
        *(float4*)&Ws[wk][wc]      = wv0;
        *(float4*)&Ws[wk + 16][wc] = wv1;
        __syncthreads();
        #pragma unroll
        for (int kk = 0; kk < 32; ++kk) {
            float4 a = *(const float4*)&As[kk][ty * 4];
            float4 b = *(const float4*)&Ws[kk][tx * 4];
            acc[0][0] += a.x*b.x; acc[0][1] += a.x*b.y; acc[0][2] += a.x*b.z; acc[0][3] += a.x*b.w;
            acc[1][0] += a.y*b.x; acc[1][1] += a.y*b.y; acc[1][2] += a.y*b.z; acc[1][3] += a.y*b.w;
            acc[2][0] += a.z*b.x; acc[2][1] += a.z*b.y; acc[2][2] += a.z*b.z; acc[2][3] += a.z*b.w;
            acc[3][0] += a.w*b.x; acc[3][1] += a.w*b.y; acc[3][2] += a.w*b.z; acc[3][3] += a.w*b.w;
        }
    }
    #pragma unroll
    for (int i = 0; i < 4; ++i) {
        const int row = row0 + ty * 4 + i;
        float4 cv = make_float4(acc[i][0], acc[i][1], acc[i][2], acc[i][3]);
        if (bias) {
            cv.x += bias[col0 + tx*4 + 0]; cv.y += bias[col0 + tx*4 + 1];
            cv.z += bias[col0 + tx*4 + 2]; cv.w += bias[col0 + tx*4 + 3];
        }
        if (relu) {
            cv.x = fmaxf(cv.x, 0.f); cv.y = fmaxf(cv.y, 0.f);
            cv.z = fmaxf(cv.z, 0.f); cv.w = fmaxf(cv.w, 0.f);
        }
        *(float4*)&C[(size_t)row * N + col0 + tx * 4] = cv;
    }
}

// ---------------------------------------------------------------------------
// LayerNorm over last dim (256). One block per row, 256 threads.
// out = (res ? res + y : y) where y = (x-mean)*rsqrt(var+1e-5)*g + b
// ---------------------------------------------------------------------------
__global__ __launch_bounds__(256)
void ln_kernel(const float* __restrict__ T, const float* __restrict__ g,
               const float* __restrict__ beta, const float* __restrict__ res,
               float* __restrict__ out)
{
    const int r = blockIdx.x, t = threadIdx.x;
    const float x = T[(size_t)r * 256 + t];
    float s = x, s2 = x * x;
    #pragma unroll
    for (int o = 1; o < 64; o <<= 1) {
        s  += __shfl_xor(s,  o);
        s2 += __shfl_xor(s2, o);
    }
    __shared__ float red[8];
    const int w = t >> 6;
    if ((t & 63) == 0) { red[w] = s; red[4 + w] = s2; }
    __syncthreads();
    s  = red[0] + red[1] + red[2] + red[3];
    s2 = red[4] + red[5] + red[6] + red[7];
    const float mean = s * (1.f / 256.f);
    const float var  = s2 * (1.f / 256.f) - mean * mean;
    const float y = (x - mean) * rsqrtf(var + 1e-5f) * g[t] + beta[t];
    out[(size_t)r * 256 + t] = res ? (res[(size_t)r * 256 + t] + y) : y;
}

// ---------------------------------------------------------------------------
// Linear attention, one block per (stream, batch, head). 256 threads.
// NOTE: Mout may alias Q — each block loads its whole Q-slice into LDS
// before the first __syncthreads, and only this block touches that slice.
// ---------------------------------------------------------------------------
__global__ __launch_bounds__(256)
void attn_kernel(const float* __restrict__ Q, const float* __restrict__ K,
                 const float* __restrict__ V, float* __restrict__ Mout, int selfl)
{
    const int bid = blockIdx.x;
    const int h = bid & 7;
    const int b = (bid >> 3) & 255;
    const int s = bid >> 11;
    const int ss = selfl ? s : (1 - s);
    const size_t qoff = ((size_t)(s  * RM) + b * N_) * D_ + h * DH_;
    const size_t koff = ((size_t)(ss * RM) + b * N_) * D_ + h * DH_;

    __shared__ float Ks[64][32];
    __shared__ float Vs[64][32];
    __shared__ float Qs[64][33];   // +1 pad: avoid 16-way bank conflict in PV loop
    __shared__ float KV[32][32];
    __shared__ float Ksum[32];
    __shared__ float zden[64];

    const int t = threadIdx.x;
    for (int i = t; i < 64 * 32; i += 256) {
        const int m = i >> 5, d = i & 31;
        const float kx = K[koff + (size_t)m * D_ + d];
        Ks[m][d] = kx > 0.f ? kx + 1.f : __expf(kx);
        Vs[m][d] = V[koff + (size_t)m * D_ + d];
        const float qx = Q[qoff + (size_t)m * D_ + d];
        Qs[m][d] = qx > 0.f ? qx + 1.f : __expf(qx);
    }
    __syncthreads();
    if (t < 32) {
        float sacc = 0.f;
        for (int m = 0; m < 64; ++m) sacc += Ks[m][t];
        Ksum[t] = sacc;
    }
    for (int i = t; i < 32 * 32; i += 256) {
        const int d = i >> 5, e = i & 31;
        float acc = 0.f;
        for (int m = 0; m < 64; ++m) acc += Ks[m][d] * Vs[m][e];
        KV[d][e] = acc * (1.f / 64.f);
    }
    __syncthreads();
    if (t < 64) {
        float acc = 0.f;
        for (int d = 0; d < 32; ++d) acc += Qs[t][d] * Ksum[d];
        zden[t] = 1.f / (acc + 1e-6f);
    }
    __syncthreads();
    const int n = t >> 2, eg = t & 3;
    float acc[8] = {0.f,0.f,0.f,0.f,0.f,0.f,0.f,0.f};
    for (int d = 0; d < 32; ++d) {
        const float qv = Qs[n][d];
        #pragma unroll
        for (int j = 0; j < 8; ++j) acc[j] += qv * KV[d][eg * 8 + j];
    }
    const float zm = zden[n] * 64.f;
    #pragma unroll
    for (int j = 0; j < 8; ++j)
        Mout[qoff + (size_t)n * D_ + eg * 8 + j] = acc[j] * zm;
}

// ---------------------------------------------------------------------------
// Geometry: penalty[b,n,m] = clip(od,1e-10,5)/0.5 + arccos-dist/10
// One block per batch, 64 threads (one per n).
// ---------------------------------------------------------------------------
__global__ __launch_bounds__(64)
void geom_kernel(const float* __restrict__ cam, const float* __restrict__ p1,
                 const float* __restrict__ p2, float* __restrict__ pen)
{
    const int b = blockIdx.x;
    const int n = threadIdx.x;

    const float tx = cam[b*7+0], ty = cam[b*7+1], tz = cam[b*7+2];
    float qw = cam[b*7+3], qx = cam[b*7+4], qy = cam[b*7+5], qz = cam[b*7+6];
    const float qn = rsqrtf(qw*qw + qx*qx + qy*qy + qz*qz);
    qw *= qn; qx *= qn; qy *= qn; qz *= qn;
    const float r00 = 1.f - 2.f*(qy*qy + qz*qz), r01 = 2.f*(qx*qy - qw*qz), r02 = 2.f*(qx*qz + qw*qy);
    const float r10 = 2.f*(qx*qy + qw*qz), r11 = 1.f - 2.f*(qx*qx + qz*qz), r12 = 2.f*(qy*qz - qw*qx);
    const float r20 = 2.f*(qx*qz - qw*qy), r21 = 2.f*(qy*qz + qw*qx), r22 = 1.f - 2.f*(qx*qx + qy*qy);

    // p1 row n, FLIP = (1,-1,-1)
    const float px =  p1[((size_t)b*64 + n)*3 + 0];
    const float py = -p1[((size_t)b*64 + n)*3 + 1];
    const float pz = -p1[((size_t)b*64 + n)*3 + 2];
    const float ex = r00*px + r01*py + r02*pz;
    const float ey = r10*px + r11*py + r12*pz;
    const float ez = r20*px + r21*py + r22*pz;
    const float el2 = ex*ex + ey*ey + ez*ez;
    const float el  = sqrtf(el2);
    float den = el + 1e-5f; den = den * den;
    // p1_r (tran = 0)
    const float sr  = el2 / den;
    const float prx = sr*ex, pry = sr*ey, prz = sr*ez;
    const float prl = fmaxf(sqrtf(prx*prx + pry*pry + prz*prz), 1e-12f);
    const float n1rx = prx/prl, n1ry = pry/prl, n1rz = prz/prl;
    // p1_rt (with tran)
    const float dot_eb = (ex+tx)*ex + (ey+ty)*ey + (ez+tz)*ez;
    const float st  = dot_eb / den;
    const float ptx = st*ex, pty = st*ey, ptz = st*ez;
    const float o1  = sqrtf(ptx*ptx + pty*pty + ptz*ptz);
    const float ptl = fmaxf(o1, 1e-12f);
    const float n1tx = ptx/ptl, n1ty = pty/ptl, n1tz = ptz/ptl;
    // p2 row n
    const float ux =  p2[((size_t)b*64 + n)*3 + 0];
    const float uy = -p2[((size_t)b*64 + n)*3 + 1];
    const float uz = -p2[((size_t)b*64 + n)*3 + 2];
    const float o2 = sqrtf(ux*ux + uy*uy + uz*uz);
    const float ul = fmaxf(o2, 1e-12f);

    __shared__ float S[64][4];   // n2x, n2y, n2z, o2
    S[n][0] = ux/ul; S[n][1] = uy/ul; S[n][2] = uz/ul; S[n][3] = o2;
    __syncthreads();

    const float RAD2DEG = 57.295779513082323f;
    for (int m = 0; m < 64; ++m) {
        const float nx = S[m][0], ny = S[m][1], nz = S[m][2], o2m = S[m][3];
        float cosr = n1rx*nx + n1ry*ny + n1rz*nz;
        cosr = fminf(fmaxf(cosr, -1.f), 1.f);
        const float ndist = acosf(cosr) * RAD2DEG;
        const float cost = n1tx*nx + n1ty*ny + n1tz*nz;
        float od = (cost < 0.f) ? fabsf(o1 + o2m) : fabsf(o1 - o2m);
        od = fminf(fmaxf(od, 1e-10f), 5.f);
        pen[((size_t)b*64 + n)*64 + m] = od * 2.f + ndist * 0.1f;
    }
}

// ---------------------------------------------------------------------------
// Z build: Z[b,n,m] = d1[b,n,:]·d2[b,m,:]/16 - pen[b,n,m]; borders = bin.
// One block per batch, 256 threads, K tiled by 64.
// ---------------------------------------------------------------------------
__global__ __launch_bounds__(256)
void zbuild_kernel(const float* __restrict__ dfeat, const float* __restrict__ pen,
                   const float* __restrict__ binp, float* __restrict__ Z)
{
    const int b = blockIdx.x;
    const float* d1 = dfeat + (size_t)(b * 64) * 256;
    const float* d2 = dfeat + (size_t)(RM + b * 64) * 256;
    __shared__ float D1[64][65], D2[64][65];
    const int tid = threadIdx.x;
    const int txx = tid & 15, tyy = tid >> 4;
    float acc[4][4] = {{0.f,0.f,0.f,0.f},{0.f,0.f,0.f,0.f},
                       {0.f,0.f,0.f,0.f},{0.f,0.f,0.f,0.f}};
    for (int c0 = 0; c0 < 256; c0 += 64) {
        __syncthreads();
        for (int i = tid; i < 64 * 64; i += 256) {
            const int r = i >> 6, c = i & 63;
            D1[r][c] = d1[(size_t)r * 256 + c0 + c];
            D2[r][c] = d2[(size_t)r * 256 + c0 + c];
        }
        __syncthreads();
        for (int c = 0; c < 64; ++c) {
            const float a0 = D1[tyy*4+0][c], a1 = D1[tyy*4+1][c];
            const float a2 = D1[tyy*4+2][c], a3 = D1[tyy*4+3][c];
            const float b0 = D2[txx*4+0][c], b1 = D2[txx*4+1][c];
            const float b2 = D2[txx*4+2][c], b3 = D2[txx*4+3][c];
            acc[0][0] += a0*b0; acc[0][1] += a0*b1; acc[0][2] += a0*b2; acc[0][3] += a0*b3;
            acc[1][0] += a1*b0; acc[1][1] += a1*b1; acc[1][2] += a1*b2; acc[1][3] += a1*b3;
            acc[2][0] += a2*b0; acc[2][1] += a2*b1; acc[2][2] += a2*b2; acc[2][3] += a2*b3;
            acc[3][0] += a3*b0; acc[3][1] += a3*b1; acc[3][2] += a3*b2; acc[3][3] += a3*b3;
        }
    }
    const float bin = *binp;
    #pragma unroll
    for (int i = 0; i < 4; ++i)
        #pragma unroll
        for (int j = 0; j < 4; ++j) {
            const int n = tyy*4 + i, m = txx*4 + j;
            Z[(size_t)b*4225 + n*65 + m] =
                acc[i][j] * (1.f/16.f) - pen[((size_t)b*64 + n)*64 + m];
        }
    if (tid < 65) Z[(size_t)b*4225 + 64*65 + tid] = bin;   // last row
    if (tid < 64) Z[(size_t)b*4225 + tid*65 + 64] = bin;   // last col
}

// ---------------------------------------------------------------------------
// Sinkhorn: 200 iterations in LDS, one block per batch. 128 threads (65 used).
// out[b,n,m] = Z[n,m] + u[n] + v[m] - norm, norm = -log(128).
// ---------------------------------------------------------------------------
__global__ __launch_bounds__(128)
void sinkhorn_kernel(const float* __restrict__ Zin, float* __restrict__ out)
{
    const int b = blockIdx.x;
    __shared__ float Zs[65][65];
    __shared__ float uu[65], vv[65];
    const int t = threadIdx.x;
    for (int i = t; i < 65 * 65; i += 128)
        Zs[i / 65][i % 65] = Zin[(size_t)b * 4225 + i];
    const float norm   = -4.8520302639196169f;   // -log(128)
    const float lmlast = -0.6931471805599453f;   // log(64)-log(128)
    if (t < 65) vv[t] = 0.f;
    __syncthreads();
    for (int it = 0; it < 200; ++it) {
        if (t < 65) {
            float m0 = Zs[t][0] + vv[0];
            for (int j = 1; j < 65; ++j) m0 = fmaxf(m0, Zs[t][j] + vv[j]);
            float ssum = 0.f;
            for (int j = 0; j < 65; ++j) ssum += __expf(Zs[t][j] + vv[j] - m0);
            uu[t] = (t < 64 ? norm : lmlast) - (m0 + __logf(ssum));
        }
        __syncthreads();
        if (t < 65) {
            float m0 = Zs[0][t] + uu[0];
            for (int i = 1; i < 65; ++i) m0 = fmaxf(m0, Zs[i][t] + uu[i]);
            float ssum = 0.f;
            for (int i = 0; i < 65; ++i) ssum += __expf(Zs[i][t] + uu[i] - m0);
            vv[t] = (t < 64 ? norm : lmlast) - (m0 + __logf(ssum));
        }
        __syncthreads();
    }
    for (int i = t; i < 65 * 65; i += 128) {
        const int n = i / 65, m = i % 65;
        out[(size_t)b * 4225 + i] = Zs[n][m] + uu[n] + vv[m] - norm;
    }
}

// ---------------------------------------------------------------------------
extern "C" void kernel_launch(void* const* d_in, const int* in_sizes, int n_in,
                              void* d_out, int out_size, void* d_ws, size_t ws_size,
                              hipStream_t stream)
{
    const float* planeApp1 = (const float*)d_in[0];
    const float* planeApp2 = (const float*)d_in[1];
    const float* cam       = (const float*)d_in[2];
    const float* p1        = (const float*)d_in[3];
    const float* p2        = (const float*)d_in[4];
    const float* app_W     = (const float*)d_in[5];
    const float* app_b     = (const float*)d_in[6];
    const float* desc_W    = (const float*)d_in[7];
    const float* desc_b    = (const float*)d_in[8];
    const float* bin_score = (const float*)d_in[9];
    const float* Wq        = (const float*)d_in[10];
    const float* Wk        = (const float*)d_in[11];
    const float* Wv        = (const float*)d_in[12];
    const float* Wm        = (const float*)d_in[13];
    const float* W1        = (const float*)d_in[14];
    const float* W2        = (const float*)d_in[15];
    const float* ln1g      = (const float*)d_in[16];
    const float* ln1b      = (const float*)d_in[17];
    const float* ln2g      = (const float*)d_in[18];
    const float* ln2b      = (const float*)d_in[19];

    float* ws = (float*)d_ws;
    const size_t SZ = (size_t)RM2 * D_;          // 8,388,608 floats
    // Workspace guard: 5 activation buffers + penalty. If ws_size is too
    // small, do NOT launch (clean correctness failure instead of GPU fault).
    const size_t need_bytes = (5 * SZ + (size_t)B_ * 64 * 64) * sizeof(float);
    if (ws_size < need_bytes) return;

    float* Xb   = ws;                            // activations (2 streams)
    float* Qb   = Xb + SZ;                       // q; then msg (aliased); then t2; then Z
    float* Kb   = Qb + SZ;                       // k; then hbuf lower half
    float* Vb   = Kb + SZ;                       // v; then hbuf upper half
    float* Tb   = Vb + SZ;                       // Wm/LN1 output
    float* pen  = Tb + SZ;                       // B*64*64
    float* Mb   = Qb;                            // msg aliases Qb (see attn note)
    float* hbuf = Kb;                            // needs 2*SZ: Kb+Vb
    float* Zb   = Qb;                            // Z aliases Qb (desc dead after zbuild reads)
    float* outp = (float*)d_out;

    const dim3 thr(256);

    geom_kernel<<<B_, 64, 0, stream>>>(cam, p1, p2, pen);

    gemm_kernel<<<dim3(RM / 64, D_ / 64), thr, 0, stream>>>(
        planeApp1, nullptr, app_W, app_b, Xb, RM, D_, D_, 0);
    gemm_kernel<<<dim3(RM / 64, D_ / 64), thr, 0, stream>>>(
        planeApp2, nullptr, app_W, app_b, Xb + (size_t)RM * D_, RM, D_, D_, 0);

    for (int i = 0; i < L_; ++i) {
        const int selfl = (i % 2 == 0) ? 1 : 0;
        const float* wq = Wq + (size_t)i * D_ * D_;
        const float* wk = Wk + (size_t)i * D_ * D_;
        const float* wv = Wv + (size_t)i * D_ * D_;
        const float* wm = Wm + (size_t)i * D_ * D_;
        const float* w1 = W1 + (size_t)i * 512 * 512;
        const float* w2 = W2 + (size_t)i * 512 * 256;

        gemm_kernel<<<dim3(RM2 / 64, D_ / 64), thr, 0, stream>>>(
            Xb, nullptr, wq, nullptr, Qb, RM2, D_, D_, 0);
        gemm_kernel<<<dim3(RM2 / 64, D_ / 64), thr, 0, stream>>>(
            Xb, nullptr, wk, nullptr, Kb, RM2, D_, D_, 0);
        gemm_kernel<<<dim3(RM2 / 64, D_ / 64), thr, 0, stream>>>(
            Xb, nullptr, wv, nullptr, Vb, RM2, D_, D_, 0);

        // msg written over Qb (safe: per-block Q fully staged to LDS first)
        attn_kernel<<<2 * B_ * 8, thr, 0, stream>>>(Qb, Kb, Vb, Mb, selfl);

        gemm_kernel<<<dim3(RM2 / 64, D_ / 64), thr, 0, stream>>>(
            Mb, nullptr, wm, nullptr, Tb, RM2, D_, D_, 0);
        ln_kernel<<<RM2, thr, 0, stream>>>(Tb, ln1g + i * 256, ln1b + i * 256,
                                           nullptr, Tb);
        // h = relu([X | Tb] @ W1)  (K=512, N=512) -> hbuf (= Kb..Vb, dead)
        gemm_kernel<<<dim3(RM2 / 64, 512 / 64), thr, 0, stream>>>(
            Xb, Tb, w1, nullptr, hbuf, RM2, 512, 512, 1);
        // t2 = h @ W2 (K=512, N=256) -> Qb (msg dead)
        gemm_kernel<<<dim3(RM2 / 64, D_ / 64), thr, 0, stream>>>(
            hbuf, nullptr, w2, nullptr, Qb, RM2, D_, 512, 0);
        // X += LN(t2)*g2 + b2
        ln_kernel<<<RM2, thr, 0, stream>>>(Qb, ln2g + i * 256, ln2b + i * 256,
                                           Xb, Xb);
    }

    // descriptors -> Tb (free)
    gemm_kernel<<<dim3(RM2 / 64, D_ / 64), thr, 0, stream>>>(
        Xb, nullptr, desc_W, desc_b, Tb, RM2, D_, D_, 0);

    zbuild_kernel<<<B_, thr, 0, stream>>>(Tb, pen, bin_score, Zb);
    sinkhorn_kernel<<<B_, 128, 0, stream>>>(Zb, outp);
}

// Round 4
// 3982.792 us; speedup vs baseline: 3.4720x; 3.4720x over previous
//
#include <hip/hip_runtime.h>
#include <math.h>
#include <stddef.h>
#include <stdint.h>

typedef unsigned short u16;
typedef unsigned int   u32;

static constexpr int B_   = 256;
static constexpr int N_   = 64;
static constexpr int D_   = 256;
static constexpr int L_   = 18;
static constexpr int RM   = B_ * N_;      // 16384 rows per stream
static constexpr int RM2  = 2 * RM;       // 32768 rows (both streams)
static constexpr size_t SZb = (size_t)RM2 * D_;   // 8,388,608 elements

typedef __attribute__((ext_vector_type(8))) short bf16x8;
typedef __attribute__((ext_vector_type(4))) float f32x4;

__device__ __forceinline__ float b2f(u16 u) {
    return __uint_as_float(((u32)u) << 16);
}
__device__ __forceinline__ u16 f2b(float f) {
    u32 x = __float_as_uint(f);
    return (u16)((x + 0x7FFFu + ((x >> 16) & 1u)) >> 16);
}
__device__ __forceinline__ void gl_lds16(const void* g, void* l) {
    __builtin_amdgcn_global_load_lds(
        (const __attribute__((address_space(1))) u32*)g,
        (__attribute__((address_space(3))) u32*)l, 16, 0, 0);
}

// ---------------------------------------------------------------------------
// bf16 MFMA GEMM. C[M,N] = act(A[M,K] @ B[K,N] (+bias)).
// B supplied TRANSPOSED: Bt[N,K] bf16. Tile 128x128, BK=64, 4 waves.
// A row-major bf16 (stride = K, or 256 in CONCAT mode: A = [A1|A2]).
// Output buffer select: cbase = C + (col0/splitn)*M*splitn (lets one GEMM
// with N=768 write 3 contiguous [M,256] buffers: fused QKV).
// MFMA 16x16x32 fragment layout: A row=lane&15,k=(lane>>4)*8+j;
// Bt col=lane&15,k likewise; C/D col=lane&15,row=(lane>>4)*4+reg (m89).
// ---------------------------------------------------------------------------
template<int CONCAT, int RELU, int BIAS, int OUTF, int OUTB>
__global__ __launch_bounds__(256)
void mgemm(const u16* __restrict__ A1, const u16* __restrict__ A2,
           const u16* __restrict__ Bt, const float* __restrict__ bias,
           float* __restrict__ Cf, u16* __restrict__ Cb,
           int M, int K, int splitn)
{
    __shared__ u16 As[128 * 64];
    __shared__ u16 Bs[128 * 64];
    const int tid  = threadIdx.x;
    const int w    = tid >> 6;
    const int lane = tid & 63;
    const int wr   = w >> 1, wc = w & 1;
    const int row0 = blockIdx.x * 128;
    const int col0 = blockIdx.y * 128;
    const int lr   = lane & 15;
    const int lk   = (lane >> 4) * 8;
    const int srow = lane >> 3;          // staging: row within 8-row chunk
    const int schk = (lane & 7) * 8;     // staging: k-element offset

    f32x4 acc[4][4];
    #pragma unroll
    for (int m = 0; m < 4; ++m)
        #pragma unroll
        for (int n = 0; n < 4; ++n)
            acc[m][n] = (f32x4){0.f, 0.f, 0.f, 0.f};

    for (int k0 = 0; k0 < K; k0 += 64) {
        const u16* Aeff; int kloc, lda;
        if (CONCAT) {
            if (k0 < 256) { Aeff = A1; kloc = k0; } else { Aeff = A2; kloc = k0 - 256; }
            lda = 256;
        } else { Aeff = A1; kloc = k0; lda = K; }
        #pragma unroll
        for (int q = 0; q < 4; ++q) {
            const int i = w * 4 + q;     // 16 chunks of 8 rows each
            gl_lds16(Aeff + (size_t)(row0 + i * 8 + srow) * lda + kloc + schk,
                     &As[i * 512]);
            gl_lds16(Bt + (size_t)(col0 + i * 8 + srow) * K + k0 + schk,
                     &Bs[i * 512]);
        }
        __syncthreads();                 // drains vmcnt(0)
        #pragma unroll
        for (int kk = 0; kk < 2; ++kk) {
            bf16x8 af[4], bfr[4];
            #pragma unroll
            for (int m = 0; m < 4; ++m)
                af[m] = *(const bf16x8*)&As[(wr * 64 + m * 16 + lr) * 64 + kk * 32 + lk];
            #pragma unroll
            for (int n = 0; n < 4; ++n)
                bfr[n] = *(const bf16x8*)&Bs[(wc * 64 + n * 16 + lr) * 64 + kk * 32 + lk];
            #pragma unroll
            for (int m = 0; m < 4; ++m)
                #pragma unroll
                for (int n = 0; n < 4; ++n)
                    acc[m][n] = __builtin_amdgcn_mfma_f32_16x16x32_bf16(
                        af[m], bfr[n], acc[m][n], 0, 0, 0);
        }
        __syncthreads();
    }

    const size_t cbase = (size_t)(col0 / splitn) * (size_t)M * splitn;
    const int lc0 = col0 % splitn;
    #pragma unroll
    for (int m = 0; m < 4; ++m) {
        #pragma unroll
        for (int n = 0; n < 4; ++n) {
            const int gc = lc0 + wc * 64 + n * 16 + (lane & 15);
            #pragma unroll
            for (int r = 0; r < 4; ++r) {
                const int gr = row0 + wr * 64 + m * 16 + (lane >> 4) * 4 + r;
                float v = acc[m][n][r];
                if (BIAS) v += bias[gc];
                if (RELU) v = fmaxf(v, 0.f);
                const size_t idx = cbase + (size_t)gr * splitn + gc;
                if (OUTF) Cf[idx] = v;
                if (OUTB) Cb[idx] = f2b(v);
            }
        }
    }
}

// ---------------------------------------------------------------------------
// Transpose+convert: W fp32 [K,N] (per layer) -> Wt bf16 [N,K].
// 64x64 tiles, 256 threads. row_off shifts output rows (QKV packing).
// ---------------------------------------------------------------------------
__global__ __launch_bounds__(256)
void wtrans_kernel(const float* __restrict__ W, u16* __restrict__ Wt,
                   int K, int N, size_t in_lstride, size_t out_lstride,
                   int row_off, int ldk)
{
    __shared__ float T[64][65];
    const int k0 = blockIdx.x * 64, n0 = blockIdx.y * 64, l = blockIdx.z;
    const int t = threadIdx.x;
    const int r = t >> 2, c0 = (t & 3) * 16;
    const float* src = W + (size_t)l * in_lstride;
    #pragma unroll
    for (int q = 0; q < 4; ++q) {
        float4 v = *(const float4*)&src[(size_t)(k0 + r) * N + n0 + c0 + q * 4];
        T[r][c0 + q * 4 + 0] = v.x; T[r][c0 + q * 4 + 1] = v.y;
        T[r][c0 + q * 4 + 2] = v.z; T[r][c0 + q * 4 + 3] = v.w;
    }
    __syncthreads();
    u16 tmp[16];
    #pragma unroll
    for (int i = 0; i < 16; ++i) tmp[i] = f2b(T[c0 + i][r]);
    u16* dst = Wt + (size_t)l * out_lstride + (size_t)(row_off + n0 + r) * ldk + k0 + c0;
    *(uint4*)&dst[0] = *(const uint4*)&tmp[0];
    *(uint4*)&dst[8] = *(const uint4*)&tmp[8];
}

// elementwise fp32 -> bf16 (n multiple of 4)
__global__ __launch_bounds__(256)
void cvt_kernel(const float* __restrict__ src, u16* __restrict__ dst, int n4)
{
    int i = blockIdx.x * 256 + threadIdx.x;
    if (i >= n4) return;
    float4 v = *(const float4*)&src[(size_t)i * 4];
    u16 o[4] = {f2b(v.x), f2b(v.y), f2b(v.z), f2b(v.w)};
    *(uint2*)&dst[(size_t)i * 4] = *(const uint2*)&o[0];
}

// ---------------------------------------------------------------------------
// LayerNorm over last dim 256, one row per block. Input fp32.
// RES=0: outb = bf16(LN). RES=1: resf += LN (fp32 master) and outb = bf16.
// ---------------------------------------------------------------------------
template<int RES>
__global__ __launch_bounds__(256)
void ln_kernel(const float* __restrict__ T, const float* __restrict__ g,
               const float* __restrict__ beta, float* __restrict__ resf,
               u16* __restrict__ outb)
{
    const int r = blockIdx.x, t = threadIdx.x;
    const size_t idx = (size_t)r * 256 + t;
    const float x = T[idx];
    float s = x, s2 = x * x;
    #pragma unroll
    for (int o = 1; o < 64; o <<= 1) {
        s  += __shfl_xor(s,  o);
        s2 += __shfl_xor(s2, o);
    }
    __shared__ float red[8];
    const int w = t >> 6;
    if ((t & 63) == 0) { red[w] = s; red[4 + w] = s2; }
    __syncthreads();
    s  = red[0] + red[1] + red[2] + red[3];
    s2 = red[4] + red[5] + red[6] + red[7];
    const float mean = s * (1.f / 256.f);
    const float var  = s2 * (1.f / 256.f) - mean * mean;
    const float y = (x - mean) * rsqrtf(var + 1e-5f) * g[t] + beta[t];
    if (RES) {
        const float o = resf[idx] + y;
        resf[idx] = o;
        outb[idx] = f2b(o);
    } else {
        outb[idx] = f2b(y);
    }
}

// ---------------------------------------------------------------------------
// Linear attention (bf16 in/out, fp32 compute). One block per (s,b,h).
// Mout may alias Q: Q staged fully to LDS before the first sync; only the
// owning block reads its own Q slice.
// ---------------------------------------------------------------------------
__global__ __launch_bounds__(256)
void attn_kernel(const u16* __restrict__ Q, const u16* __restrict__ K,
                 const u16* __restrict__ V, u16* __restrict__ Mout, int selfl)
{
    const int bid = blockIdx.x;
    const int h = bid & 7;
    const int b = (bid >> 3) & 255;
    const int s = bid >> 11;
    const int ss = selfl ? s : (1 - s);
    const size_t qoff = ((size_t)(s  * RM) + b * N_) * D_ + h * 32;
    const size_t koff = ((size_t)(ss * RM) + b * N_) * D_ + h * 32;

    __shared__ float Ks[64][32];
    __shared__ float Vs[64][32];
    __shared__ float Qs[64][33];
    __shared__ float KV[32][32];
    __shared__ float Ksum[32];
    __shared__ float zden[64];

    const int t = threadIdx.x;
    {   // vectorized load: 256 threads x 8 bf16 per matrix
        const int m = t >> 2, d0 = (t & 3) * 8;
        uint4 kq = *(const uint4*)&K[koff + (size_t)m * D_ + d0];
        uint4 vq = *(const uint4*)&V[koff + (size_t)m * D_ + d0];
        uint4 qq = *(const uint4*)&Q[qoff + (size_t)m * D_ + d0];
        const u16* kp = (const u16*)&kq;
        const u16* vp = (const u16*)&vq;
        const u16* qp = (const u16*)&qq;
        #pragma unroll
        for (int j = 0; j < 8; ++j) {
            float kx = b2f(kp[j]);
            Ks[m][d0 + j] = kx > 0.f ? kx + 1.f : __expf(kx);
            Vs[m][d0 + j] = b2f(vp[j]);
            float qx = b2f(qp[j]);
            Qs[m][d0 + j] = qx > 0.f ? qx + 1.f : __expf(qx);
        }
    }
    __syncthreads();
    if (t < 32) {
        float sacc = 0.f;
        for (int m = 0; m < 64; ++m) sacc += Ks[m][t];
        Ksum[t] = sacc;
    }
    for (int i = t; i < 32 * 32; i += 256) {
        const int d = i >> 5, e = i & 31;
        float acc = 0.f;
        for (int m = 0; m < 64; ++m) acc += Ks[m][d] * Vs[m][e];
        KV[d][e] = acc * (1.f / 64.f);
    }
    __syncthreads();
    if (t < 64) {
        float acc = 0.f;
        for (int d = 0; d < 32; ++d) acc += Qs[t][d] * Ksum[d];
        zden[t] = 1.f / (acc + 1e-6f);
    }
    __syncthreads();
    const int n = t >> 2, eg = t & 3;
    float acc[8] = {0.f,0.f,0.f,0.f,0.f,0.f,0.f,0.f};
    for (int d = 0; d < 32; ++d) {
        const float qv = Qs[n][d];
        #pragma unroll
        for (int j = 0; j < 8; ++j) acc[j] += qv * KV[d][eg * 8 + j];
    }
    const float zm = zden[n] * 64.f;
    u16 o[8];
    #pragma unroll
    for (int j = 0; j < 8; ++j) o[j] = f2b(acc[j] * zm);
    *(uint4*)&Mout[qoff + (size_t)n * D_ + eg * 8] = *(const uint4*)&o[0];
}

// ---------------------------------------------------------------------------
// Geometry penalty (unchanged, fp32): pen = od*2 + ndist*0.1
// ---------------------------------------------------------------------------
__global__ __launch_bounds__(64)
void geom_kernel(const float* __restrict__ cam, const float* __restrict__ p1,
                 const float* __restrict__ p2, float* __restrict__ pen)
{
    const int b = blockIdx.x;
    const int n = threadIdx.x;

    const float tx = cam[b*7+0], ty = cam[b*7+1], tz = cam[b*7+2];
    float qw = cam[b*7+3], qx = cam[b*7+4], qy = cam[b*7+5], qz = cam[b*7+6];
    const float qn = rsqrtf(qw*qw + qx*qx + qy*qy + qz*qz);
    qw *= qn; qx *= qn; qy *= qn; qz *= qn;
    const float r00 = 1.f - 2.f*(qy*qy + qz*qz), r01 = 2.f*(qx*qy - qw*qz), r02 = 2.f*(qx*qz + qw*qy);
    const float r10 = 2.f*(qx*qy + qw*qz), r11 = 1.f - 2.f*(qx*qx + qz*qz), r12 = 2.f*(qy*qz - qw*qx);
    const float r20 = 2.f*(qx*qz - qw*qy), r21 = 2.f*(qy*qz + qw*qx), r22 = 1.f - 2.f*(qx*qx + qy*qy);

    const float px =  p1[((size_t)b*64 + n)*3 + 0];
    const float py = -p1[((size_t)b*64 + n)*3 + 1];
    const float pz = -p1[((size_t)b*64 + n)*3 + 2];
    const float ex = r00*px + r01*py + r02*pz;
    const float ey = r10*px + r11*py + r12*pz;
    const float ez = r20*px + r21*py + r22*pz;
    const float el2 = ex*ex + ey*ey + ez*ez;
    const float el  = sqrtf(el2);
    float den = el + 1e-5f; den = den * den;
    const float sr  = el2 / den;
    const float prx = sr*ex, pry = sr*ey, prz = sr*ez;
    const float prl = fmaxf(sqrtf(prx*prx + pry*pry + prz*prz), 1e-12f);
    const float n1rx = prx/prl, n1ry = pry/prl, n1rz = prz/prl;
    const float dot_eb = (ex+tx)*ex + (ey+ty)*ey + (ez+tz)*ez;
    const float st  = dot_eb / den;
    const float ptx = st*ex, pty = st*ey, ptz = st*ez;
    const float o1  = sqrtf(ptx*ptx + pty*pty + ptz*ptz);
    const float ptl = fmaxf(o1, 1e-12f);
    const float n1tx = ptx/ptl, n1ty = pty/ptl, n1tz = ptz/ptl;
    const float ux =  p2[((size_t)b*64 + n)*3 + 0];
    const float uy = -p2[((size_t)b*64 + n)*3 + 1];
    const float uz = -p2[((size_t)b*64 + n)*3 + 2];
    const float o2 = sqrtf(ux*ux + uy*uy + uz*uz);
    const float ul = fmaxf(o2, 1e-12f);

    __shared__ float S[64][4];
    S[n][0] = ux/ul; S[n][1] = uy/ul; S[n][2] = uz/ul; S[n][3] = o2;
    __syncthreads();

    const float RAD2DEG = 57.295779513082323f;
    for (int m = 0; m < 64; ++m) {
        const float nx = S[m][0], ny = S[m][1], nz = S[m][2], o2m = S[m][3];
        float cosr = n1rx*nx + n1ry*ny + n1rz*nz;
        cosr = fminf(fmaxf(cosr, -1.f), 1.f);
        const float ndist = acosf(cosr) * RAD2DEG;
        const float cost = n1tx*nx + n1ty*ny + n1tz*nz;
        float od = (cost < 0.f) ? fabsf(o1 + o2m) : fabsf(o1 - o2m);
        od = fminf(fmaxf(od, 1e-10f), 5.f);
        pen[((size_t)b*64 + n)*64 + m] = od * 2.f + ndist * 0.1f;
    }
}

// ---------------------------------------------------------------------------
// Z build (fp32 desc): Z[b,n,m] = d1.d2/16 - pen; borders = bin.
// ---------------------------------------------------------------------------
__global__ __launch_bounds__(256)
void zbuild_kernel(const float* __restrict__ dfeat, const float* __restrict__ pen,
                   const float* __restrict__ binp, float* __restrict__ Z)
{
    const int b = blockIdx.x;
    const float* d1 = dfeat + (size_t)(b * 64) * 256;
    const float* d2 = dfeat + (size_t)(RM + b * 64) * 256;
    __shared__ float D1[64][65], D2[64][65];
    const int tid = threadIdx.x;
    const int txx = tid & 15, tyy = tid >> 4;
    float acc[4][4] = {{0.f,0.f,0.f,0.f},{0.f,0.f,0.f,0.f},
                       {0.f,0.f,0.f,0.f},{0.f,0.f,0.f,0.f}};
    for (int c0 = 0; c0 < 256; c0 += 64) {
        __syncthreads();
        for (int i = tid; i < 64 * 64; i += 256) {
            const int r = i >> 6, c = i & 63;
            D1[r][c] = d1[(size_t)r * 256 + c0 + c];
            D2[r][c] = d2[(size_t)r * 256 + c0 + c];
        }
        __syncthreads();
        for (int c = 0; c < 64; ++c) {
            const float a0 = D1[tyy*4+0][c], a1 = D1[tyy*4+1][c];
            const float a2 = D1[tyy*4+2][c], a3 = D1[tyy*4+3][c];
            const float b0 = D2[txx*4+0][c], b1 = D2[txx*4+1][c];
            const float b2 = D2[txx*4+2][c], b3 = D2[txx*4+3][c];
            acc[0][0] += a0*b0; acc[0][1] += a0*b1; acc[0][2] += a0*b2; acc[0][3] += a0*b3;
            acc[1][0] += a1*b0; acc[1][1] += a1*b1; acc[1][2] += a1*b2; acc[1][3] += a1*b3;
            acc[2][0] += a2*b0; acc[2][1] += a2*b1; acc[2][2] += a2*b2; acc[2][3] += a2*b3;
            acc[3][0] += a3*b0; acc[3][1] += a3*b1; acc[3][2] += a3*b2; acc[3][3] += a3*b3;
        }
    }
    const float bin = *binp;
    #pragma unroll
    for (int i = 0; i < 4; ++i)
        #pragma unroll
        for (int j = 0; j < 4; ++j) {
            const int n = tyy*4 + i, m = txx*4 + j;
            Z[(size_t)b*4225 + n*65 + m] =
                acc[i][j] * (1.f/16.f) - pen[((size_t)b*64 + n)*64 + m];
        }
    if (tid < 65) Z[(size_t)b*4225 + 64*65 + tid] = bin;
    if (tid < 64) Z[(size_t)b*4225 + tid*65 + 64] = bin;
}

// ---------------------------------------------------------------------------
// Sinkhorn, log2 domain. 576 threads: 8 lanes per row/col, shfl_xor
// max/sum-combine. log2_mu = -7 (rows<64) / -1 (row 64); same for nu.
// ---------------------------------------------------------------------------
__global__ __launch_bounds__(576)
void sinkhorn_kernel(const float* __restrict__ Zin, float* __restrict__ out)
{
    const int b = blockIdx.x;
    __shared__ float Zs[65][65];
    __shared__ float uu[65], vv[65];
    const int t = threadIdx.x;
    const float LOG2E = 1.4426950408889634f;
    const float LN2   = 0.69314718055994531f;
    for (int i = t; i < 65 * 65; i += 576)
        Zs[i / 65][i % 65] = Zin[(size_t)b * 4225 + i] * LOG2E;
    if (t < 65) vv[t] = 0.f;
    __syncthreads();

    const int rr = t >> 3, l8 = t & 7;
    const int active = (t < 520);
    const float mu2 = (rr < 64) ? -7.0f : -1.0f;

    for (int it = 0; it < 200; ++it) {
        if (active) {   // u update: reduce over cols of row rr
            float vals[9];
            #pragma unroll
            for (int p = 0; p < 9; ++p) {
                const int j = l8 + p * 8;
                vals[p] = (j < 65) ? (Zs[rr][j] + vv[j]) : -3.0e38f;
            }
            float m = vals[0];
            #pragma unroll
            for (int p = 1; p < 9; ++p) m = fmaxf(m, vals[p]);
            float sum = 0.f;
            #pragma unroll
            for (int p = 0; p < 9; ++p) sum += exp2f(vals[p] - m);
            #pragma unroll
            for (int o = 1; o < 8; o <<= 1) {
                const float om = __shfl_xor(m, o);
                const float os = __shfl_xor(sum, o);
                const float nm = fmaxf(m, om);
                sum = sum * exp2f(m - nm) + os * exp2f(om - nm);
                m = nm;
            }
            if (l8 == 0) uu[rr] = mu2 - (m + log2f(sum));
        }
        __syncthreads();
        if (active) {   // v update: reduce over rows of col rr
            float vals[9];
            #pragma unroll
            for (int p = 0; p < 9; ++p) {
                const int j = l8 + p * 8;
                vals[p] = (j < 65) ? (Zs[j][rr] + uu[j]) : -3.0e38f;
            }
            float m = vals[0];
            #pragma unroll
            for (int p = 1; p < 9; ++p) m = fmaxf(m, vals[p]);
            float sum = 0.f;
            #pragma unroll
            for (int p = 0; p < 9; ++p) sum += exp2f(vals[p] - m);
            #pragma unroll
            for (int o = 1; o < 8; o <<= 1) {
                const float om = __shfl_xor(m, o);
                const float os = __shfl_xor(sum, o);
                const float nm = fmaxf(m, om);
                sum = sum * exp2f(m - nm) + os * exp2f(om - nm);
                m = nm;
            }
            if (l8 == 0) vv[rr] = mu2 - (m + log2f(sum));
        }
        __syncthreads();
    }
    for (int i = t; i < 65 * 65; i += 576) {
        const int n = i / 65, m = i % 65;
        out[(size_t)b * 4225 + i] = (Zs[n][m] + uu[n] + vv[m] + 7.0f) * LN2;
    }
}

// ---------------------------------------------------------------------------
extern "C" void kernel_launch(void* const* d_in, const int* in_sizes, int n_in,
                              void* d_out, int out_size, void* d_ws, size_t ws_size,
                              hipStream_t stream)
{
    const float* planeApp1 = (const float*)d_in[0];
    const float* planeApp2 = (const float*)d_in[1];
    const float* cam       = (const float*)d_in[2];
    const float* p1        = (const float*)d_in[3];
    const float* p2        = (const float*)d_in[4];
    const float* app_W     = (const float*)d_in[5];
    const float* app_b     = (const float*)d_in[6];
    const float* desc_W    = (const float*)d_in[7];
    const float* desc_b    = (const float*)d_in[8];
    const float* bin_score = (const float*)d_in[9];
    const float* Wq        = (const float*)d_in[10];
    const float* Wk        = (const float*)d_in[11];
    const float* Wv        = (const float*)d_in[12];
    const float* Wm        = (const float*)d_in[13];
    const float* W1        = (const float*)d_in[14];
    const float* W2        = (const float*)d_in[15];
    const float* ln1g      = (const float*)d_in[16];
    const float* ln1b      = (const float*)d_in[17];
    const float* ln2g      = (const float*)d_in[18];
    const float* ln2b      = (const float*)d_in[19];

    // ---- workspace layout (bytes): 5 bf16 bufs | Xf f32 | pen | bf16 weights
    const size_t wq_elems   = (size_t)L_ * 768 * 256;   // fused QKV^T
    const size_t wm_elems   = (size_t)L_ * 256 * 256;
    const size_t w1_elems   = (size_t)L_ * 512 * 512;
    const size_t w2_elems   = (size_t)L_ * 256 * 512;
    const size_t need = 5 * SZb * 2 + SZb * 4 + (size_t)B_ * 4096 * 4 +
        (wq_elems + wm_elems + w1_elems + w2_elems + 2 * 65536) * 2;
    if (ws_size < need) return;

    u16* Xb = (u16*)d_ws;
    u16* Qb = Xb + SZb;
    u16* Kb = Qb + SZb;
    u16* Vb = Kb + SZb;
    u16* Tb = Vb + SZb;
    float* Xf  = (float*)(Tb + SZb);
    float* pen = Xf + SZb;
    u16* wqkv = (u16*)(pen + (size_t)B_ * 4096);
    u16* wmt  = wqkv + wq_elems;
    u16* w1t  = wmt + wm_elems;
    u16* w2t  = w1t + w1_elems;
    u16* appt = w2t + w2_elems;
    u16* dsct = appt + 65536;
    float* outp = (float*)d_out;

    // ---- weight transpose+convert (per launch; ~24 MB total)
    wtrans_kernel<<<dim3(4, 4, L_), 256, 0, stream>>>(Wq, wqkv, 256, 256, 65536, 768*256, 0,   256);
    wtrans_kernel<<<dim3(4, 4, L_), 256, 0, stream>>>(Wk, wqkv, 256, 256, 65536, 768*256, 256, 256);
    wtrans_kernel<<<dim3(4, 4, L_), 256, 0, stream>>>(Wv, wqkv, 256, 256, 65536, 768*256, 512, 256);
    wtrans_kernel<<<dim3(4, 4, L_), 256, 0, stream>>>(Wm, wmt,  256, 256, 65536, 65536,   0,   256);
    wtrans_kernel<<<dim3(8, 8, L_), 256, 0, stream>>>(W1, w1t,  512, 512, 262144, 262144, 0,   512);
    wtrans_kernel<<<dim3(8, 4, L_), 256, 0, stream>>>(W2, w2t,  512, 256, 131072, 131072, 0,   512);
    wtrans_kernel<<<dim3(4, 4, 1),  256, 0, stream>>>(app_W,  appt, 256, 256, 65536, 65536, 0, 256);
    wtrans_kernel<<<dim3(4, 4, 1),  256, 0, stream>>>(desc_W, dsct, 256, 256, 65536, 65536, 0, 256);

    // planeApp f32 -> bf16, both streams contiguous in Qb (scratch)
    cvt_kernel<<<(RM * D_ / 4 + 255) / 256, 256, 0, stream>>>(planeApp1, Qb, RM * D_ / 4);
    cvt_kernel<<<(RM * D_ / 4 + 255) / 256, 256, 0, stream>>>(planeApp2, Qb + (size_t)RM * D_, RM * D_ / 4);

    geom_kernel<<<B_, 64, 0, stream>>>(cam, p1, p2, pen);

    // x0 = planeApp @ app_W + app_b  -> Xf (f32 master) + Xb (bf16)
    mgemm<0,0,1,1,1><<<dim3(RM2/128, 2), 256, 0, stream>>>(
        Qb, nullptr, appt, app_b, Xf, Xb, RM2, 256, 256);

    for (int i = 0; i < L_; ++i) {
        const int selfl = (i % 2 == 0) ? 1 : 0;
        // fused QKV: N=768, splitn=256 -> writes Qb|Kb|Vb (contiguous)
        mgemm<0,0,0,0,1><<<dim3(RM2/128, 6), 256, 0, stream>>>(
            Xb, nullptr, wqkv + (size_t)i*768*256, nullptr, nullptr, Qb, RM2, 256, 256);
        // msg -> Qb (alias-safe)
        attn_kernel<<<2 * B_ * 8, 256, 0, stream>>>(Qb, Kb, Vb, Qb, selfl);
        // msg @ Wm -> f32 scratch over Kb+Vb
        mgemm<0,0,0,1,0><<<dim3(RM2/128, 2), 256, 0, stream>>>(
            Qb, nullptr, wmt + (size_t)i*65536, nullptr, (float*)Kb, nullptr, RM2, 256, 256);
        // LN1 -> Tb bf16
        ln_kernel<0><<<RM2, 256, 0, stream>>>((float*)Kb, ln1g + i*256, ln1b + i*256,
                                              nullptr, Tb);
        // h = relu([Xb|Tb] @ W1) bf16 -> Qb..Kb region ([M,512])
        mgemm<1,1,0,0,1><<<dim3(RM2/128, 4), 256, 0, stream>>>(
            Xb, Tb, w1t + (size_t)i*262144, nullptr, nullptr, Qb, RM2, 512, 512);
        // t2 = h @ W2 -> f32 over Vb+Tb region
        mgemm<0,0,0,1,0><<<dim3(RM2/128, 2), 256, 0, stream>>>(
            Qb, nullptr, w2t + (size_t)i*131072, nullptr, (float*)Vb, nullptr, RM2, 512, 256);
        // X += LN(t2): Xf (f32) + Xb (bf16)
        ln_kernel<1><<<RM2, 256, 0, stream>>>((float*)Vb, ln2g + i*256, ln2b + i*256,
                                              Xf, Xb);
    }

    // descriptors f32 -> Qb..Kb region
    mgemm<0,0,1,1,0><<<dim3(RM2/128, 2), 256, 0, stream>>>(
        Xb, nullptr, dsct, desc_b, (float*)Qb, nullptr, RM2, 256, 256);

    zbuild_kernel<<<B_, 256, 0, stream>>>((float*)Qb, pen, bin_score, (float*)Vb);
    sinkhorn_kernel<<<B_, 576, 0, stream>>>((float*)Vb, outp);
}

// Round 6
// 3336.074 us; speedup vs baseline: 4.1451x; 1.1939x over previous
//
#include <hip/hip_runtime.h>
#include <math.h>
#include <stddef.h>
#include <stdint.h>

typedef unsigned short u16;
typedef unsigned int   u32;

static constexpr int B_   = 256;
static constexpr int N_   = 64;
static constexpr int D_   = 256;
static constexpr int L_   = 18;
static constexpr int RM   = B_ * N_;      // 16384 rows per stream
static constexpr int RM2  = 2 * RM;       // 32768 rows (both streams)
static constexpr size_t SZb = (size_t)RM2 * D_;   // 8,388,608 elements

typedef __attribute__((ext_vector_type(8))) short bf16x8;
typedef __attribute__((ext_vector_type(4))) float f32x4;

__device__ __forceinline__ float b2f(u16 u) {
    return __uint_as_float(((u32)u) << 16);
}
__device__ __forceinline__ u16 f2b(float f) {
    u32 x = __float_as_uint(f);
    return (u16)((x + 0x7FFFu + ((x >> 16) & 1u)) >> 16);
}
__device__ __forceinline__ void gl_lds16(const void* g, void* l) {
    __builtin_amdgcn_global_load_lds(
        (const __attribute__((address_space(1))) u32*)g,
        (__attribute__((address_space(3))) u32*)l, 16, 0, 0);
}

// ---------------------------------------------------------------------------
// bf16 MFMA GEMM (generic). C = act(A@B (+bias)). Bt[N,K] bf16 transposed.
// Tile 128x128, BK=64, 4 waves (2x2). splitn: QKV buffer splitting.
// ---------------------------------------------------------------------------
template<int CONCAT, int RELU, int BIAS, int OUTF, int OUTB>
__global__ __launch_bounds__(256)
void mgemm(const u16* __restrict__ A1, const u16* __restrict__ A2,
           const u16* __restrict__ Bt, const float* __restrict__ bias,
           float* __restrict__ Cf, u16* __restrict__ Cb,
           int M, int K, int splitn)
{
    __shared__ u16 As[128 * 64];
    __shared__ u16 Bs[128 * 64];
    const int tid  = threadIdx.x;
    const int w    = tid >> 6;
    const int lane = tid & 63;
    const int wr   = w >> 1, wc = w & 1;
    const int row0 = blockIdx.x * 128;
    const int col0 = blockIdx.y * 128;
    const int lr   = lane & 15;
    const int lk   = (lane >> 4) * 8;
    const int srow = lane >> 3;
    const int schk = (lane & 7) * 8;

    f32x4 acc[4][4];
    #pragma unroll
    for (int m = 0; m < 4; ++m)
        #pragma unroll
        for (int n = 0; n < 4; ++n)
            acc[m][n] = (f32x4){0.f, 0.f, 0.f, 0.f};

    for (int k0 = 0; k0 < K; k0 += 64) {
        const u16* Aeff; int kloc, lda;
        if (CONCAT) {
            if (k0 < 256) { Aeff = A1; kloc = k0; } else { Aeff = A2; kloc = k0 - 256; }
            lda = 256;
        } else { Aeff = A1; kloc = k0; lda = K; }
        #pragma unroll
        for (int q = 0; q < 4; ++q) {
            const int i = w * 4 + q;
            gl_lds16(Aeff + (size_t)(row0 + i * 8 + srow) * lda + kloc + schk,
                     &As[i * 512]);
            gl_lds16(Bt + (size_t)(col0 + i * 8 + srow) * K + k0 + schk,
                     &Bs[i * 512]);
        }
        __syncthreads();
        #pragma unroll
        for (int kk = 0; kk < 2; ++kk) {
            bf16x8 af[4], bfr[4];
            #pragma unroll
            for (int m = 0; m < 4; ++m)
                af[m] = *(const bf16x8*)&As[(wr * 64 + m * 16 + lr) * 64 + kk * 32 + lk];
            #pragma unroll
            for (int n = 0; n < 4; ++n)
                bfr[n] = *(const bf16x8*)&Bs[(wc * 64 + n * 16 + lr) * 64 + kk * 32 + lk];
            #pragma unroll
            for (int m = 0; m < 4; ++m)
                #pragma unroll
                for (int n = 0; n < 4; ++n)
                    acc[m][n] = __builtin_amdgcn_mfma_f32_16x16x32_bf16(
                        af[m], bfr[n], acc[m][n], 0, 0, 0);
        }
        __syncthreads();
    }

    const size_t cbase = (size_t)(col0 / splitn) * (size_t)M * splitn;
    const int lc0 = col0 % splitn;
    #pragma unroll
    for (int m = 0; m < 4; ++m) {
        #pragma unroll
        for (int n = 0; n < 4; ++n) {
            const int gc = lc0 + wc * 64 + n * 16 + (lane & 15);
            #pragma unroll
            for (int r = 0; r < 4; ++r) {
                const int gr = row0 + wr * 64 + m * 16 + (lane >> 4) * 4 + r;
                float v = acc[m][n][r];
                if (BIAS) v += bias[gc];
                if (RELU) v = fmaxf(v, 0.f);
                const size_t idx = cbase + (size_t)gr * splitn + gc;
                if (OUTF) Cf[idx] = v;
                if (OUTB) Cb[idx] = f2b(v);
            }
        }
    }
}

// ---------------------------------------------------------------------------
// Fused GEMM + LayerNorm. N fixed = 256 (full rows in-block). BM=64, BK=64,
// 4 waves: wave w owns cols [w*64, w*64+64). Row mean/var: per-fragment sums
// -> shfl_xor(1,2,4,8) over the 16-lane col group -> cross-wave LDS combine.
// RES=0: outb = bf16(LN(acc)).  RES=1: resf += LN(acc); outb = bf16(resf).
// ---------------------------------------------------------------------------
template<int RES>
__global__ __launch_bounds__(256)
void mgemm_ln(const u16* __restrict__ A, const u16* __restrict__ Bt,
              const float* __restrict__ g, const float* __restrict__ beta,
              float* __restrict__ resf, u16* __restrict__ outb, int K)
{
    __shared__ u16 As[64 * 64];
    __shared__ u16 Bs[256 * 64];
    __shared__ float rs[4][64], rq[4][64];
    const int tid  = threadIdx.x;
    const int w    = tid >> 6;
    const int lane = tid & 63;
    const int row0 = blockIdx.x * 64;
    const int lr   = lane & 15;
    const int lk   = (lane >> 4) * 8;
    const int srow = lane >> 3;
    const int schk = (lane & 7) * 8;

    f32x4 acc[4][4];
    #pragma unroll
    for (int m = 0; m < 4; ++m)
        #pragma unroll
        for (int n = 0; n < 4; ++n)
            acc[m][n] = (f32x4){0.f, 0.f, 0.f, 0.f};

    for (int k0 = 0; k0 < K; k0 += 64) {
        #pragma unroll
        for (int q = 0; q < 2; ++q) {
            const int i = w * 2 + q;     // 8 A-chunks of 8 rows
            gl_lds16(A + (size_t)(row0 + i * 8 + srow) * K + k0 + schk,
                     &As[i * 512]);
        }
        #pragma unroll
        for (int q = 0; q < 8; ++q) {
            const int i = w * 8 + q;     // 32 B-chunks of 8 rows
            gl_lds16(Bt + (size_t)(i * 8 + srow) * K + k0 + schk,
                     &Bs[i * 512]);
        }
        __syncthreads();
        #pragma unroll
        for (int kk = 0; kk < 2; ++kk) {
            bf16x8 af[4], bfr[4];
            #pragma unroll
            for (int m = 0; m < 4; ++m)
                af[m] = *(const bf16x8*)&As[(m * 16 + lr) * 64 + kk * 32 + lk];
            #pragma unroll
            for (int n = 0; n < 4; ++n)
                bfr[n] = *(const bf16x8*)&Bs[(w * 64 + n * 16 + lr) * 64 + kk * 32 + lk];
            #pragma unroll
            for (int m = 0; m < 4; ++m)
                #pragma unroll
                for (int n = 0; n < 4; ++n)
                    acc[m][n] = __builtin_amdgcn_mfma_f32_16x16x32_bf16(
                        af[m], bfr[n], acc[m][n], 0, 0, 0);
        }
        __syncthreads();
    }

    // --- per-row partial sums (this wave's 64 cols) ---
    #pragma unroll
    for (int m = 0; m < 4; ++m) {
        #pragma unroll
        for (int r = 0; r < 4; ++r) {
            float s  = acc[m][0][r] + acc[m][1][r] + acc[m][2][r] + acc[m][3][r];
            float s2 = acc[m][0][r]*acc[m][0][r] + acc[m][1][r]*acc[m][1][r]
                     + acc[m][2][r]*acc[m][2][r] + acc[m][3][r]*acc[m][3][r];
            #pragma unroll
            for (int o = 1; o < 16; o <<= 1) {
                s  += __shfl_xor(s,  o);
                s2 += __shfl_xor(s2, o);
            }
            if ((lane & 15) == 0) {
                const int row = m * 16 + (lane >> 4) * 4 + r;
                rs[w][row] = s; rq[w][row] = s2;
            }
        }
    }
    __syncthreads();
    if (tid < 64) {
        const float s = rs[0][tid] + rs[1][tid] + rs[2][tid] + rs[3][tid];
        const float q = rq[0][tid] + rq[1][tid] + rq[2][tid] + rq[3][tid];
        const float mean = s * (1.f / 256.f);
        const float var  = q * (1.f / 256.f) - mean * mean;
        rs[0][tid] = mean;
        rq[0][tid] = rsqrtf(var + 1e-5f);
    }
    __syncthreads();

    float gc[4], bc[4];
    #pragma unroll
    for (int n = 0; n < 4; ++n) {
        const int col = w * 64 + n * 16 + lr;
        gc[n] = g[col]; bc[n] = beta[col];
    }
    #pragma unroll
    for (int m = 0; m < 4; ++m) {
        #pragma unroll
        for (int r = 0; r < 4; ++r) {
            const int row  = m * 16 + (lane >> 4) * 4 + r;
            const float mean = rs[0][row], inv = rq[0][row];
            const int gr = row0 + row;
            #pragma unroll
            for (int n = 0; n < 4; ++n) {
                const int col = w * 64 + n * 16 + lr;
                const size_t idx = (size_t)gr * 256 + col;
                float y = (acc[m][n][r] - mean) * inv * gc[n] + bc[n];
                if (RES) {
                    const float o = resf[idx] + y;
                    resf[idx] = o;
                    outb[idx] = f2b(o);
                } else {
                    outb[idx] = f2b(y);
                }
            }
        }
    }
}

// ---------------------------------------------------------------------------
// Transpose+convert: W fp32 [K,N] (per layer) -> Wt bf16 [N,K].
// ---------------------------------------------------------------------------
__global__ __launch_bounds__(256)
void wtrans_kernel(const float* __restrict__ W, u16* __restrict__ Wt,
                   int K, int N, size_t in_lstride, size_t out_lstride,
                   int row_off, int ldk)
{
    __shared__ float T[64][65];
    const int k0 = blockIdx.x * 64, n0 = blockIdx.y * 64, l = blockIdx.z;
    const int t = threadIdx.x;
    const int r = t >> 2, c0 = (t & 3) * 16;
    const float* src = W + (size_t)l * in_lstride;
    #pragma unroll
    for (int q = 0; q < 4; ++q) {
        float4 v = *(const float4*)&src[(size_t)(k0 + r) * N + n0 + c0 + q * 4];
        T[r][c0 + q * 4 + 0] = v.x; T[r][c0 + q * 4 + 1] = v.y;
        T[r][c0 + q * 4 + 2] = v.z; T[r][c0 + q * 4 + 3] = v.w;
    }
    __syncthreads();
    u16 tmp[16];
    #pragma unroll
    for (int i = 0; i < 16; ++i) tmp[i] = f2b(T[c0 + i][r]);
    u16* dst = Wt + (size_t)l * out_lstride + (size_t)(row_off + n0 + r) * ldk + k0 + c0;
    *(uint4*)&dst[0] = *(const uint4*)&tmp[0];
    *(uint4*)&dst[8] = *(const uint4*)&tmp[8];
}

// elementwise fp32 -> bf16
__global__ __launch_bounds__(256)
void cvt_kernel(const float* __restrict__ src, u16* __restrict__ dst, int n4)
{
    int i = blockIdx.x * 256 + threadIdx.x;
    if (i >= n4) return;
    float4 v = *(const float4*)&src[(size_t)i * 4];
    u16 o[4] = {f2b(v.x), f2b(v.y), f2b(v.z), f2b(v.w)};
    *(uint2*)&dst[(size_t)i * 4] = *(const uint2*)&o[0];
}

// ---------------------------------------------------------------------------
// Linear attention (bf16 in/out, fp32 compute). One block per (s,b,h).
// Mout may alias Q (Q fully staged to LDS before first sync).
// ---------------------------------------------------------------------------
__global__ __launch_bounds__(256)
void attn_kernel(const u16* __restrict__ Q, const u16* __restrict__ K,
                 const u16* __restrict__ V, u16* __restrict__ Mout, int selfl)
{
    const int bid = blockIdx.x;
    const int h = bid & 7;
    const int b = (bid >> 3) & 255;
    const int s = bid >> 11;
    const int ss = selfl ? s : (1 - s);
    const size_t qoff = ((size_t)(s  * RM) + b * N_) * D_ + h * 32;
    const size_t koff = ((size_t)(ss * RM) + b * N_) * D_ + h * 32;

    __shared__ float Ks[64][32];
    __shared__ float Vs[64][32];
    __shared__ float Qs[64][33];
    __shared__ float KV[32][32];
    __shared__ float Ksum[32];
    __shared__ float zden[64];

    const int t = threadIdx.x;
    {
        const int m = t >> 2, d0 = (t & 3) * 8;
        uint4 kq = *(const uint4*)&K[koff + (size_t)m * D_ + d0];
        uint4 vq = *(const uint4*)&V[koff + (size_t)m * D_ + d0];
        uint4 qq = *(const uint4*)&Q[qoff + (size_t)m * D_ + d0];
        const u16* kp = (const u16*)&kq;
        const u16* vp = (const u16*)&vq;
        const u16* qp = (const u16*)&qq;
        #pragma unroll
        for (int j = 0; j < 8; ++j) {
            float kx = b2f(kp[j]);
            Ks[m][d0 + j] = kx > 0.f ? kx + 1.f : __expf(kx);
            Vs[m][d0 + j] = b2f(vp[j]);
            float qx = b2f(qp[j]);
            Qs[m][d0 + j] = qx > 0.f ? qx + 1.f : __expf(qx);
        }
    }
    __syncthreads();
    if (t < 32) {
        float sacc = 0.f;
        for (int m = 0; m < 64; ++m) sacc += Ks[m][t];
        Ksum[t] = sacc;
    }
    for (int i = t; i < 32 * 32; i += 256) {
        const int d = i >> 5, e = i & 31;
        float acc = 0.f;
        for (int m = 0; m < 64; ++m) acc += Ks[m][d] * Vs[m][e];
        KV[d][e] = acc * (1.f / 64.f);
    }
    __syncthreads();
    if (t < 64) {
        float acc = 0.f;
        for (int d = 0; d < 32; ++d) acc += Qs[t][d] * Ksum[d];
        zden[t] = 1.f / (acc + 1e-6f);
    }
    __syncthreads();
    const int n = t >> 2, eg = t & 3;
    float acc[8] = {0.f,0.f,0.f,0.f,0.f,0.f,0.f,0.f};
    for (int d = 0; d < 32; ++d) {
        const float qv = Qs[n][d];
        #pragma unroll
        for (int j = 0; j < 8; ++j) acc[j] += qv * KV[d][eg * 8 + j];
    }
    const float zm = zden[n] * 64.f;
    u16 o[8];
    #pragma unroll
    for (int j = 0; j < 8; ++j) o[j] = f2b(acc[j] * zm);
    *(uint4*)&Mout[qoff + (size_t)n * D_ + eg * 8] = *(const uint4*)&o[0];
}

// ---------------------------------------------------------------------------
// Geometry penalty: pen = od*2 + ndist*0.1
// ---------------------------------------------------------------------------
__global__ __launch_bounds__(64)
void geom_kernel(const float* __restrict__ cam, const float* __restrict__ p1,
                 const float* __restrict__ p2, float* __restrict__ pen)
{
    const int b = blockIdx.x;
    const int n = threadIdx.x;

    const float tx = cam[b*7+0], ty = cam[b*7+1], tz = cam[b*7+2];
    float qw = cam[b*7+3], qx = cam[b*7+4], qy = cam[b*7+5], qz = cam[b*7+6];
    const float qn = rsqrtf(qw*qw + qx*qx + qy*qy + qz*qz);
    qw *= qn; qx *= qn; qy *= qn; qz *= qn;
    const float r00 = 1.f - 2.f*(qy*qy + qz*qz), r01 = 2.f*(qx*qy - qw*qz), r02 = 2.f*(qx*qz + qw*qy);
    const float r10 = 2.f*(qx*qy + qw*qz), r11 = 1.f - 2.f*(qx*qx + qz*qz), r12 = 2.f*(qy*qz - qw*qx);
    const float r20 = 2.f*(qx*qz - qw*qy), r21 = 2.f*(qy*qz + qw*qx), r22 = 1.f - 2.f*(qx*qx + qy*qy);

    const float px =  p1[((size_t)b*64 + n)*3 + 0];
    const float py = -p1[((size_t)b*64 + n)*3 + 1];
    const float pz = -p1[((size_t)b*64 + n)*3 + 2];
    const float ex = r00*px + r01*py + r02*pz;
    const float ey = r10*px + r11*py + r12*pz;
    const float ez = r20*px + r21*py + r22*pz;
    const float el2 = ex*ex + ey*ey + ez*ez;
    const float el  = sqrtf(el2);
    float den = el + 1e-5f; den = den * den;
    const float sr  = el2 / den;
    const float prx = sr*ex, pry = sr*ey, prz = sr*ez;
    const float prl = fmaxf(sqrtf(prx*prx + pry*pry + prz*prz), 1e-12f);
    const float n1rx = prx/prl, n1ry = pry/prl, n1rz = prz/prl;
    const float dot_eb = (ex+tx)*ex + (ey+ty)*ey + (ez+tz)*ez;
    const float st  = dot_eb / den;
    const float ptx = st*ex, pty = st*ey, ptz = st*ez;
    const float o1  = sqrtf(ptx*ptx + pty*pty + ptz*ptz);
    const float ptl = fmaxf(o1, 1e-12f);
    const float n1tx = ptx/ptl, n1ty = pty/ptl, n1tz = ptz/ptl;
    const float ux =  p2[((size_t)b*64 + n)*3 + 0];
    const float uy = -p2[((size_t)b*64 + n)*3 + 1];
    const float uz = -p2[((size_t)b*64 + n)*3 + 2];
    const float o2 = sqrtf(ux*ux + uy*uy + uz*uz);
    const float ul = fmaxf(o2, 1e-12f);

    __shared__ float S[64][4];
    S[n][0] = ux/ul; S[n][1] = uy/ul; S[n][2] = uz/ul; S[n][3] = o2;
    __syncthreads();

    const float RAD2DEG = 57.295779513082323f;
    for (int m = 0; m < 64; ++m) {
        const float nx = S[m][0], ny = S[m][1], nz = S[m][2], o2m = S[m][3];
        float cosr = n1rx*nx + n1ry*ny + n1rz*nz;
        cosr = fminf(fmaxf(cosr, -1.f), 1.f);
        const float ndist = acosf(cosr) * RAD2DEG;
        const float cost = n1tx*nx + n1ty*ny + n1tz*nz;
        float od = (cost < 0.f) ? fabsf(o1 + o2m) : fabsf(o1 - o2m);
        od = fminf(fmaxf(od, 1e-10f), 5.f);
        pen[((size_t)b*64 + n)*64 + m] = od * 2.f + ndist * 0.1f;
    }
}

// ---------------------------------------------------------------------------
// Z build (fp32 desc): Z[b,n,m] = d1.d2/16 - pen; borders = bin.
// ---------------------------------------------------------------------------
__global__ __launch_bounds__(256)
void zbuild_kernel(const float* __restrict__ dfeat, const float* __restrict__ pen,
                   const float* __restrict__ binp, float* __restrict__ Z)
{
    const int b = blockIdx.x;
    const float* d1 = dfeat + (size_t)(b * 64) * 256;
    const float* d2 = dfeat + (size_t)(RM + b * 64) * 256;
    __shared__ float D1[64][65], D2[64][65];
    const int tid = threadIdx.x;
    const int txx = tid & 15, tyy = tid >> 4;
    float acc[4][4] = {{0.f,0.f,0.f,0.f},{0.f,0.f,0.f,0.f},
                       {0.f,0.f,0.f,0.f},{0.f,0.f,0.f,0.f}};
    for (int c0 = 0; c0 < 256; c0 += 64) {
        __syncthreads();
        for (int i = tid; i < 64 * 64; i += 256) {
            const int r = i >> 6, c = i & 63;
            D1[r][c] = d1[(size_t)r * 256 + c0 + c];
            D2[r][c] = d2[(size_t)r * 256 + c0 + c];
        }
        __syncthreads();
        for (int c = 0; c < 64; ++c) {
            const float a0 = D1[tyy*4+0][c], a1 = D1[tyy*4+1][c];
            const float a2 = D1[tyy*4+2][c], a3 = D1[tyy*4+3][c];
            const float b0 = D2[txx*4+0][c], b1 = D2[txx*4+1][c];
            const float b2 = D2[txx*4+2][c], b3 = D2[txx*4+3][c];
            acc[0][0] += a0*b0; acc[0][1] += a0*b1; acc[0][2] += a0*b2; acc[0][3] += a0*b3;
            acc[1][0] += a1*b0; acc[1][1] += a1*b1; acc[1][2] += a1*b2; acc[1][3] += a1*b3;
            acc[2][0] += a2*b0; acc[2][1] += a2*b1; acc[2][2] += a2*b2; acc[2][3] += a2*b3;
            acc[3][0] += a3*b0; acc[3][1] += a3*b1; acc[3][2] += a3*b2; acc[3][3] += a3*b3;
        }
    }
    const float bin = *binp;
    #pragma unroll
    for (int i = 0; i < 4; ++i)
        #pragma unroll
        for (int j = 0; j < 4; ++j) {
            const int n = tyy*4 + i, m = txx*4 + j;
            Z[(size_t)b*4225 + n*65 + m] =
                acc[i][j] * (1.f/16.f) - pen[((size_t)b*64 + n)*64 + m];
        }
    if (tid < 65) Z[(size_t)b*4225 + 64*65 + tid] = bin;
    if (tid < 64) Z[(size_t)b*4225 + tid*65 + 64] = bin;
}

// ---------------------------------------------------------------------------
// Sinkhorn, log2 domain, Z fully register-resident (row+col slices; Z is
// constant across iterations). LDS holds only uu/vv (broadcast reads).
// 8 lanes per row/col, shfl_xor(1,2,4) max/sum combine.
// ---------------------------------------------------------------------------
__global__ __launch_bounds__(576)
void sinkhorn_kernel(const float* __restrict__ Zin, float* __restrict__ out)
{
    const int b = blockIdx.x;
    __shared__ float uu[65], vv[65];
    const int t  = threadIdx.x;
    const int rr = t >> 3, l8 = t & 7;
    const int act = (rr < 65);
    const float LOG2E = 1.4426950408889634f;
    const float LN2   = 0.69314718055994531f;

    float zrow[9], zcol[9];
    #pragma unroll
    for (int p = 0; p < 9; ++p) {
        const int j = l8 + p * 8;
        const int ok = act && (j < 65);
        zrow[p] = ok ? Zin[(size_t)b * 4225 + rr * 65 + j] * LOG2E : -3.0e38f;
        zcol[p] = ok ? Zin[(size_t)b * 4225 + j * 65 + rr] * LOG2E : -3.0e38f;
    }
    if (t < 65) vv[t] = 0.f;
    __syncthreads();

    const float mu2 = (rr < 64) ? -7.0f : -1.0f;

    for (int it = 0; it < 200; ++it) {
        {   // u update
            float m = -3.0e38f, sum = 0.f, vals[9];
            #pragma unroll
            for (int p = 0; p < 9; ++p) {
                const int j = l8 + p * 8;
                vals[p] = zrow[p] + vv[j < 65 ? j : 0];
                m = fmaxf(m, vals[p]);
            }
            #pragma unroll
            for (int p = 0; p < 9; ++p) sum += exp2f(vals[p] - m);
            #pragma unroll
            for (int o = 1; o < 8; o <<= 1) {
                const float om = __shfl_xor(m, o);
                const float os = __shfl_xor(sum, o);
                const float nm = fmaxf(m, om);
                sum = sum * exp2f(m - nm) + os * exp2f(om - nm);
                m = nm;
            }
            if (act && l8 == 0) uu[rr] = mu2 - (m + log2f(sum));
        }
        __syncthreads();
        {   // v update
            float m = -3.0e38f, sum = 0.f, vals[9];
            #pragma unroll
            for (int p = 0; p < 9; ++p) {
                const int j = l8 + p * 8;
                vals[p] = zcol[p] + uu[j < 65 ? j : 0];
                m = fmaxf(m, vals[p]);
            }
            #pragma unroll
            for (int p = 0; p < 9; ++p) sum += exp2f(vals[p] - m);
            #pragma unroll
            for (int o = 1; o < 8; o <<= 1) {
                const float om = __shfl_xor(m, o);
                const float os = __shfl_xor(sum, o);
                const float nm = fmaxf(m, om);
                sum = sum * exp2f(m - nm) + os * exp2f(om - nm);
                m = nm;
            }
            if (act && l8 == 0) vv[rr] = mu2 - (m + log2f(sum));
        }
        __syncthreads();
    }
    if (act) {
        const float ur = uu[rr];
        #pragma unroll
        for (int p = 0; p < 9; ++p) {
            const int j = l8 + p * 8;
            if (j < 65)
                out[(size_t)b * 4225 + rr * 65 + j] =
                    (zrow[p] + ur + vv[j] + 7.0f) * LN2;
        }
    }
}

// ---------------------------------------------------------------------------
extern "C" void kernel_launch(void* const* d_in, const int* in_sizes, int n_in,
                              void* d_out, int out_size, void* d_ws, size_t ws_size,
                              hipStream_t stream)
{
    const float* planeApp1 = (const float*)d_in[0];
    const float* planeApp2 = (const float*)d_in[1];
    const float* cam       = (const float*)d_in[2];
    const float* p1        = (const float*)d_in[3];
    const float* p2        = (const float*)d_in[4];
    const float* app_W     = (const float*)d_in[5];
    const float* app_b     = (const float*)d_in[6];
    const float* desc_W    = (const float*)d_in[7];
    const float* desc_b    = (const float*)d_in[8];
    const float* bin_score = (const float*)d_in[9];
    const float* Wq        = (const float*)d_in[10];
    const float* Wk        = (const float*)d_in[11];
    const float* Wv        = (const float*)d_in[12];
    const float* Wm        = (const float*)d_in[13];
    const float* W1        = (const float*)d_in[14];
    const float* W2        = (const float*)d_in[15];
    const float* ln1g      = (const float*)d_in[16];
    const float* ln1b      = (const float*)d_in[17];
    const float* ln2g      = (const float*)d_in[18];
    const float* ln2b      = (const float*)d_in[19];

    const size_t wq_elems   = (size_t)L_ * 768 * 256;
    const size_t wm_elems   = (size_t)L_ * 256 * 256;
    const size_t w1_elems   = (size_t)L_ * 512 * 512;
    const size_t w2_elems   = (size_t)L_ * 256 * 512;
    const size_t need = 5 * SZb * 2 + SZb * 4 + (size_t)B_ * 4096 * 4 +
        (wq_elems + wm_elems + w1_elems + w2_elems + 2 * 65536) * 2;
    if (ws_size < need) return;

    u16* Xb = (u16*)d_ws;
    u16* Qb = Xb + SZb;
    u16* Kb = Qb + SZb;
    u16* Vb = Kb + SZb;
    u16* Tb = Vb + SZb;
    float* Xf  = (float*)(Tb + SZb);
    float* pen = Xf + SZb;
    u16* wqkv = (u16*)(pen + (size_t)B_ * 4096);
    u16* wmt  = wqkv + wq_elems;
    u16* w1t  = wmt + wm_elems;
    u16* w2t  = w1t + w1_elems;
    u16* appt = w2t + w2_elems;
    u16* dsct = appt + 65536;
    float* outp = (float*)d_out;

    // ---- weight transpose+convert
    wtrans_kernel<<<dim3(4, 4, L_), 256, 0, stream>>>(Wq, wqkv, 256, 256, 65536, 768*256, 0,   256);
    wtrans_kernel<<<dim3(4, 4, L_), 256, 0, stream>>>(Wk, wqkv, 256, 256, 65536, 768*256, 256, 256);
    wtrans_kernel<<<dim3(4, 4, L_), 256, 0, stream>>>(Wv, wqkv, 256, 256, 65536, 768*256, 512, 256);
    wtrans_kernel<<<dim3(4, 4, L_), 256, 0, stream>>>(Wm, wmt,  256, 256, 65536, 65536,   0,   256);
    wtrans_kernel<<<dim3(8, 8, L_), 256, 0, stream>>>(W1, w1t,  512, 512, 262144, 262144, 0,   512);
    wtrans_kernel<<<dim3(8, 4, L_), 256, 0, stream>>>(W2, w2t,  512, 256, 131072, 131072, 0,   512);
    wtrans_kernel<<<dim3(4, 4, 1),  256, 0, stream>>>(app_W,  appt, 256, 256, 65536, 65536, 0, 256);
    wtrans_kernel<<<dim3(4, 4, 1),  256, 0, stream>>>(desc_W, dsct, 256, 256, 65536, 65536, 0, 256);

    cvt_kernel<<<(RM * D_ / 4 + 255) / 256, 256, 0, stream>>>(planeApp1, Qb, RM * D_ / 4);
    cvt_kernel<<<(RM * D_ / 4 + 255) / 256, 256, 0, stream>>>(planeApp2, Qb + (size_t)RM * D_, RM * D_ / 4);

    geom_kernel<<<B_, 64, 0, stream>>>(cam, p1, p2, pen);

    // x0 = planeApp @ app_W + app_b  -> Xf + Xb
    mgemm<0,0,1,1,1><<<dim3(RM2/128, 2), 256, 0, stream>>>(
        Qb, nullptr, appt, app_b, Xf, Xb, RM2, 256, 256);

    for (int i = 0; i < L_; ++i) {
        const int selfl = (i % 2 == 0) ? 1 : 0;
        // fused QKV -> Qb|Kb|Vb
        mgemm<0,0,0,0,1><<<dim3(RM2/128, 6), 256, 0, stream>>>(
            Xb, nullptr, wqkv + (size_t)i*768*256, nullptr, nullptr, Qb, RM2, 256, 256);
        // msg -> Qb (alias-safe)
        attn_kernel<<<2 * B_ * 8, 256, 0, stream>>>(Qb, Kb, Vb, Qb, selfl);
        // Wm + LN1 fused -> Tb (bf16)
        mgemm_ln<0><<<RM2/64, 256, 0, stream>>>(
            Qb, wmt + (size_t)i*65536, ln1g + i*256, ln1b + i*256,
            nullptr, Tb, 256);
        // h = relu([Xb|Tb] @ W1) -> Qb..Kb region ([M,512] bf16)
        mgemm<1,1,0,0,1><<<dim3(RM2/128, 4), 256, 0, stream>>>(
            Xb, Tb, w1t + (size_t)i*262144, nullptr, nullptr, Qb, RM2, 512, 512);
        // W2 + LN2 + residual fused: Xf += LN(h@W2), Xb = bf16(Xf)
        mgemm_ln<1><<<RM2/64, 256, 0, stream>>>(
            Qb, w2t + (size_t)i*131072, ln2g + i*256, ln2b + i*256,
            Xf, Xb, 512);
    }

    // descriptors f32 -> Qb..Kb region
    mgemm<0,0,1,1,0><<<dim3(RM2/128, 2), 256, 0, stream>>>(
        Xb, nullptr, dsct, desc_b, (float*)Qb, nullptr, RM2, 256, 256);

    zbuild_kernel<<<B_, 256, 0, stream>>>((float*)Qb, pen, bin_score, (float*)Vb);
    sinkhorn_kernel<<<B_, 576, 0, stream>>>((float*)Vb, outp);
}

// Round 7
// 3174.672 us; speedup vs baseline: 4.3558x; 1.0508x over previous
//
#include <hip/hip_runtime.h>
#include <math.h>
#include <stddef.h>
#include <stdint.h>

typedef unsigned short u16;
typedef unsigned int   u32;

static constexpr int B_   = 256;
static constexpr int N_   = 64;
static constexpr int D_   = 256;
static constexpr int L_   = 18;
static constexpr int RM   = B_ * N_;      // 16384 rows per stream
static constexpr int RM2  = 2 * RM;       // 32768 rows (both streams)
static constexpr size_t SZb = (size_t)RM2 * D_;   // 8,388,608 elements

typedef __attribute__((ext_vector_type(8))) short bf16x8;
typedef __attribute__((ext_vector_type(4))) float f32x4;

__device__ __forceinline__ float b2f(u16 u) {
    return __uint_as_float(((u32)u) << 16);
}
__device__ __forceinline__ u16 f2b(float f) {
    u32 x = __float_as_uint(f);
    return (u16)((x + 0x7FFFu + ((x >> 16) & 1u)) >> 16);
}
__device__ __forceinline__ void gl_lds16(const void* g, void* l) {
    __builtin_amdgcn_global_load_lds(
        (const __attribute__((address_space(1))) u32*)g,
        (__attribute__((address_space(3))) u32*)l, 16, 0, 0);
}

// ---------------------------------------------------------------------------
// bf16 MFMA GEMM, 2-phase double-buffered: stage(t+1) issued BEFORE compute(t),
// ONE __syncthreads per K-step (drains the in-flight prefetch cheaply).
// Tile 128x128, BK=64, 4 waves. Bt[N,K] transposed. splitn: fused-QKV split.
// ---------------------------------------------------------------------------
template<int K, int CONCAT, int RELU, int BIAS, int OUTF, int OUTB>
__global__ __launch_bounds__(256)
void mgemm(const u16* __restrict__ A1, const u16* __restrict__ A2,
           const u16* __restrict__ Bt, const float* __restrict__ bias,
           float* __restrict__ Cf, u16* __restrict__ Cb,
           int M, int splitn)
{
    constexpr int NT = K / 64;
    __shared__ u16 As[2][128 * 64];
    __shared__ u16 Bs[2][128 * 64];
    const int tid  = threadIdx.x;
    const int w    = tid >> 6;
    const int lane = tid & 63;
    const int wr   = w >> 1, wc = w & 1;
    const int row0 = blockIdx.x * 128;
    const int col0 = blockIdx.y * 128;
    const int lr   = lane & 15;
    const int lk   = (lane >> 4) * 8;
    const int srow = lane >> 3;
    const int schk = (lane & 7) * 8;

    auto stage = [&](int t, int buf) {
        const int k0 = t * 64;
        const u16* Aeff; int kloc, lda;
        if (CONCAT) {
            if (k0 < 256) { Aeff = A1; kloc = k0; } else { Aeff = A2; kloc = k0 - 256; }
            lda = 256;
        } else { Aeff = A1; kloc = k0; lda = K; }
        #pragma unroll
        for (int q = 0; q < 4; ++q) {
            const int i = w * 4 + q;     // 16 chunks of 8 rows each
            gl_lds16(Aeff + (size_t)(row0 + i * 8 + srow) * lda + kloc + schk,
                     &As[buf][i * 512]);
            gl_lds16(Bt + (size_t)(col0 + i * 8 + srow) * K + t * 64 + schk,
                     &Bs[buf][i * 512]);
        }
    };

    f32x4 acc[4][4];
    #pragma unroll
    for (int m = 0; m < 4; ++m)
        #pragma unroll
        for (int n = 0; n < 4; ++n)
            acc[m][n] = (f32x4){0.f, 0.f, 0.f, 0.f};

    stage(0, 0);
    __syncthreads();
    #pragma unroll
    for (int t = 0; t < NT; ++t) {
        const int cur = t & 1;
        if (t + 1 < NT) stage(t + 1, cur ^ 1);
        #pragma unroll
        for (int kk = 0; kk < 2; ++kk) {
            bf16x8 af[4], bfr[4];
            #pragma unroll
            for (int m = 0; m < 4; ++m)
                af[m] = *(const bf16x8*)&As[cur][(wr * 64 + m * 16 + lr) * 64 + kk * 32 + lk];
            #pragma unroll
            for (int n = 0; n < 4; ++n)
                bfr[n] = *(const bf16x8*)&Bs[cur][(wc * 64 + n * 16 + lr) * 64 + kk * 32 + lk];
            #pragma unroll
            for (int m = 0; m < 4; ++m)
                #pragma unroll
                for (int n = 0; n < 4; ++n)
                    acc[m][n] = __builtin_amdgcn_mfma_f32_16x16x32_bf16(
                        af[m], bfr[n], acc[m][n], 0, 0, 0);
        }
        __syncthreads();
    }

    const size_t cbase = (size_t)(col0 / splitn) * (size_t)M * splitn;
    const int lc0 = col0 % splitn;
    #pragma unroll
    for (int m = 0; m < 4; ++m) {
        #pragma unroll
        for (int n = 0; n < 4; ++n) {
            const int gc = lc0 + wc * 64 + n * 16 + (lane & 15);
            #pragma unroll
            for (int r = 0; r < 4; ++r) {
                const int gr = row0 + wr * 64 + m * 16 + (lane >> 4) * 4 + r;
                float v = acc[m][n][r];
                if (BIAS) v += bias[gc];
                if (RELU) v = fmaxf(v, 0.f);
                const size_t idx = cbase + (size_t)gr * splitn + gc;
                if (OUTF) Cf[idx] = v;
                if (OUTB) Cb[idx] = f2b(v);
            }
        }
    }
}

// ---------------------------------------------------------------------------
// Fused GEMM + LayerNorm, 2-phase double-buffered. N fixed = 256 (full rows
// in-block). BM=128, BK=64, 8 waves (2 row-halves x 4 col-groups).
// Row mean/var: per-fragment sums -> 16-lane shfl reduce -> cross-wave LDS.
// RES=0: outb = bf16(LN(acc)).  RES=1: resf += LN(acc); outb = bf16(resf).
// ---------------------------------------------------------------------------
template<int K, int RES>
__global__ __launch_bounds__(512)
void mgemm_ln(const u16* __restrict__ A, const u16* __restrict__ Bt,
              const float* __restrict__ g, const float* __restrict__ beta,
              float* __restrict__ resf, u16* __restrict__ outb)
{
    constexpr int NT = K / 64;
    __shared__ u16 As[2][128 * 64];
    __shared__ u16 Bs[2][256 * 64];
    __shared__ float rs[4][128], rq[4][128];
    const int tid  = threadIdx.x;
    const int w    = tid >> 6;           // 0..7
    const int lane = tid & 63;
    const int wr   = w >> 2, wc = w & 3; // 2 x 4 wave grid
    const int row0 = blockIdx.x * 128;
    const int lr   = lane & 15;
    const int lk   = (lane >> 4) * 8;
    const int srow = lane >> 3;
    const int schk = (lane & 7) * 8;

    auto stage = [&](int t, int buf) {
        #pragma unroll
        for (int q = 0; q < 2; ++q) {
            const int i = w * 2 + q;     // 16 A-chunks of 8 rows
            gl_lds16(A + (size_t)(row0 + i * 8 + srow) * K + t * 64 + schk,
                     &As[buf][i * 512]);
        }
        #pragma unroll
        for (int q = 0; q < 4; ++q) {
            const int i = w * 4 + q;     // 32 B-chunks of 8 rows
            gl_lds16(Bt + (size_t)(i * 8 + srow) * K + t * 64 + schk,
                     &Bs[buf][i * 512]);
        }
    };

    f32x4 acc[4][4];
    #pragma unroll
    for (int m = 0; m < 4; ++m)
        #pragma unroll
        for (int n = 0; n < 4; ++n)
            acc[m][n] = (f32x4){0.f, 0.f, 0.f, 0.f};

    stage(0, 0);
    __syncthreads();
    #pragma unroll
    for (int t = 0; t < NT; ++t) {
        const int cur = t & 1;
        if (t + 1 < NT) stage(t + 1, cur ^ 1);
        #pragma unroll
        for (int kk = 0; kk < 2; ++kk) {
            bf16x8 af[4], bfr[4];
            #pragma unroll
            for (int m = 0; m < 4; ++m)
                af[m] = *(const bf16x8*)&As[cur][(wr * 64 + m * 16 + lr) * 64 + kk * 32 + lk];
            #pragma unroll
            for (int n = 0; n < 4; ++n)
                bfr[n] = *(const bf16x8*)&Bs[cur][(wc * 64 + n * 16 + lr) * 64 + kk * 32 + lk];
            #pragma unroll
            for (int m = 0; m < 4; ++m)
                #pragma unroll
                for (int n = 0; n < 4; ++n)
                    acc[m][n] = __builtin_amdgcn_mfma_f32_16x16x32_bf16(
                        af[m], bfr[n], acc[m][n], 0, 0, 0);
        }
        __syncthreads();
    }

    // --- per-row partial sums (this wave's 64 cols) ---
    #pragma unroll
    for (int m = 0; m < 4; ++m) {
        #pragma unroll
        for (int r = 0; r < 4; ++r) {
            float s  = acc[m][0][r] + acc[m][1][r] + acc[m][2][r] + acc[m][3][r];
            float s2 = acc[m][0][r]*acc[m][0][r] + acc[m][1][r]*acc[m][1][r]
                     + acc[m][2][r]*acc[m][2][r] + acc[m][3][r]*acc[m][3][r];
            #pragma unroll
            for (int o = 1; o < 16; o <<= 1) {
                s  += __shfl_xor(s,  o);
                s2 += __shfl_xor(s2, o);
            }
            if ((lane & 15) == 0) {
                const int row = wr * 64 + m * 16 + (lane >> 4) * 4 + r;
                rs[wc][row] = s; rq[wc][row] = s2;
            }
        }
    }
    __syncthreads();
    if (tid < 128) {
        const float s = rs[0][tid] + rs[1][tid] + rs[2][tid] + rs[3][tid];
        const float q = rq[0][tid] + rq[1][tid] + rq[2][tid] + rq[3][tid];
        const float mean = s * (1.f / 256.f);
        const float var  = q * (1.f / 256.f) - mean * mean;
        rs[0][tid] = mean;
        rq[0][tid] = rsqrtf(var + 1e-5f);
    }
    __syncthreads();

    float gc[4], bc[4];
    #pragma unroll
    for (int n = 0; n < 4; ++n) {
        const int col = wc * 64 + n * 16 + lr;
        gc[n] = g[col]; bc[n] = beta[col];
    }
    #pragma unroll
    for (int m = 0; m < 4; ++m) {
        #pragma unroll
        for (int r = 0; r < 4; ++r) {
            const int row  = wr * 64 + m * 16 + (lane >> 4) * 4 + r;
            const float mean = rs[0][row], inv = rq[0][row];
            const int gr = row0 + row;
            #pragma unroll
            for (int n = 0; n < 4; ++n) {
                const int col = wc * 64 + n * 16 + lr;
                const size_t idx = (size_t)gr * 256 + col;
                float y = (acc[m][n][r] - mean) * inv * gc[n] + bc[n];
                if (RES) {
                    const float o = resf[idx] + y;
                    resf[idx] = o;
                    outb[idx] = f2b(o);
                } else {
                    outb[idx] = f2b(y);
                }
            }
        }
    }
}

// ---------------------------------------------------------------------------
// Transpose+convert: W fp32 [K,N] (per layer) -> Wt bf16 [N,K].
// ---------------------------------------------------------------------------
__global__ __launch_bounds__(256)
void wtrans_kernel(const float* __restrict__ W, u16* __restrict__ Wt,
                   int K, int N, size_t in_lstride, size_t out_lstride,
                   int row_off, int ldk)
{
    __shared__ float T[64][65];
    const int k0 = blockIdx.x * 64, n0 = blockIdx.y * 64, l = blockIdx.z;
    const int t = threadIdx.x;
    const int r = t >> 2, c0 = (t & 3) * 16;
    const float* src = W + (size_t)l * in_lstride;
    #pragma unroll
    for (int q = 0; q < 4; ++q) {
        float4 v = *(const float4*)&src[(size_t)(k0 + r) * N + n0 + c0 + q * 4];
        T[r][c0 + q * 4 + 0] = v.x; T[r][c0 + q * 4 + 1] = v.y;
        T[r][c0 + q * 4 + 2] = v.z; T[r][c0 + q * 4 + 3] = v.w;
    }
    __syncthreads();
    u16 tmp[16];
    #pragma unroll
    for (int i = 0; i < 16; ++i) tmp[i] = f2b(T[c0 + i][r]);
    u16* dst = Wt + (size_t)l * out_lstride + (size_t)(row_off + n0 + r) * ldk + k0 + c0;
    *(uint4*)&dst[0] = *(const uint4*)&tmp[0];
    *(uint4*)&dst[8] = *(const uint4*)&tmp[8];
}

// elementwise fp32 -> bf16
__global__ __launch_bounds__(256)
void cvt_kernel(const float* __restrict__ src, u16* __restrict__ dst, int n4)
{
    int i = blockIdx.x * 256 + threadIdx.x;
    if (i >= n4) return;
    float4 v = *(const float4*)&src[(size_t)i * 4];
    u16 o[4] = {f2b(v.x), f2b(v.y), f2b(v.z), f2b(v.w)};
    *(uint2*)&dst[(size_t)i * 4] = *(const uint2*)&o[0];
}

// ---------------------------------------------------------------------------
// Linear attention (bf16 in/out, fp32 compute). One block per (s,b,h).
// Mout may alias Q (Q fully staged to LDS before first sync).
// ---------------------------------------------------------------------------
__global__ __launch_bounds__(256)
void attn_kernel(const u16* __restrict__ Q, const u16* __restrict__ K,
                 const u16* __restrict__ V, u16* __restrict__ Mout, int selfl)
{
    const int bid = blockIdx.x;
    const int h = bid & 7;
    const int b = (bid >> 3) & 255;
    const int s = bid >> 11;
    const int ss = selfl ? s : (1 - s);
    const size_t qoff = ((size_t)(s  * RM) + b * N_) * D_ + h * 32;
    const size_t koff = ((size_t)(ss * RM) + b * N_) * D_ + h * 32;

    __shared__ float Ks[64][32];
    __shared__ float Vs[64][32];
    __shared__ float Qs[64][33];
    __shared__ float KV[32][32];
    __shared__ float Ksum[32];
    __shared__ float zden[64];

    const int t = threadIdx.x;
    {
        const int m = t >> 2, d0 = (t & 3) * 8;
        uint4 kq = *(const uint4*)&K[koff + (size_t)m * D_ + d0];
        uint4 vq = *(const uint4*)&V[koff + (size_t)m * D_ + d0];
        uint4 qq = *(const uint4*)&Q[qoff + (size_t)m * D_ + d0];
        const u16* kp = (const u16*)&kq;
        const u16* vp = (const u16*)&vq;
        const u16* qp = (const u16*)&qq;
        #pragma unroll
        for (int j = 0; j < 8; ++j) {
            float kx = b2f(kp[j]);
            Ks[m][d0 + j] = kx > 0.f ? kx + 1.f : __expf(kx);
            Vs[m][d0 + j] = b2f(vp[j]);
            float qx = b2f(qp[j]);
            Qs[m][d0 + j] = qx > 0.f ? qx + 1.f : __expf(qx);
        }
    }
    __syncthreads();
    if (t < 32) {
        float sacc = 0.f;
        for (int m = 0; m < 64; ++m) sacc += Ks[m][t];
        Ksum[t] = sacc;
    }
    for (int i = t; i < 32 * 32; i += 256) {
        const int d = i >> 5, e = i & 31;
        float acc = 0.f;
        for (int m = 0; m < 64; ++m) acc += Ks[m][d] * Vs[m][e];
        KV[d][e] = acc * (1.f / 64.f);
    }
    __syncthreads();
    if (t < 64) {
        float acc = 0.f;
        for (int d = 0; d < 32; ++d) acc += Qs[t][d] * Ksum[d];
        zden[t] = 1.f / (acc + 1e-6f);
    }
    __syncthreads();
    const int n = t >> 2, eg = t & 3;
    float acc[8] = {0.f,0.f,0.f,0.f,0.f,0.f,0.f,0.f};
    for (int d = 0; d < 32; ++d) {
        const float qv = Qs[n][d];
        #pragma unroll
        for (int j = 0; j < 8; ++j) acc[j] += qv * KV[d][eg * 8 + j];
    }
    const float zm = zden[n] * 64.f;
    u16 o[8];
    #pragma unroll
    for (int j = 0; j < 8; ++j) o[j] = f2b(acc[j] * zm);
    *(uint4*)&Mout[qoff + (size_t)n * D_ + eg * 8] = *(const uint4*)&o[0];
}

// ---------------------------------------------------------------------------
// Geometry penalty: pen = od*2 + ndist*0.1
// ---------------------------------------------------------------------------
__global__ __launch_bounds__(64)
void geom_kernel(const float* __restrict__ cam, const float* __restrict__ p1,
                 const float* __restrict__ p2, float* __restrict__ pen)
{
    const int b = blockIdx.x;
    const int n = threadIdx.x;

    const float tx = cam[b*7+0], ty = cam[b*7+1], tz = cam[b*7+2];
    float qw = cam[b*7+3], qx = cam[b*7+4], qy = cam[b*7+5], qz = cam[b*7+6];
    const float qn = rsqrtf(qw*qw + qx*qx + qy*qy + qz*qz);
    qw *= qn; qx *= qn; qy *= qn; qz *= qn;
    const float r00 = 1.f - 2.f*(qy*qy + qz*qz), r01 = 2.f*(qx*qy - qw*qz), r02 = 2.f*(qx*qz + qw*qy);
    const float r10 = 2.f*(qx*qy + qw*qz), r11 = 1.f - 2.f*(qx*qx + qz*qz), r12 = 2.f*(qy*qz - qw*qx);
    const float r20 = 2.f*(qx*qz - qw*qy), r21 = 2.f*(qy*qz + qw*qx), r22 = 1.f - 2.f*(qx*qx + qy*qy);

    const float px =  p1[((size_t)b*64 + n)*3 + 0];
    const float py = -p1[((size_t)b*64 + n)*3 + 1];
    const float pz = -p1[((size_t)b*64 + n)*3 + 2];
    const float ex = r00*px + r01*py + r02*pz;
    const float ey = r10*px + r11*py + r12*pz;
    const float ez = r20*px + r21*py + r22*pz;
    const float el2 = ex*ex + ey*ey + ez*ez;
    const float el  = sqrtf(el2);
    float den = el + 1e-5f; den = den * den;
    const float sr  = el2 / den;
    const float prx = sr*ex, pry = sr*ey, prz = sr*ez;
    const float prl = fmaxf(sqrtf(prx*prx + pry*pry + prz*prz), 1e-12f);
    const float n1rx = prx/prl, n1ry = pry/prl, n1rz = prz/prl;
    const float dot_eb = (ex+tx)*ex + (ey+ty)*ey + (ez+tz)*ez;
    const float st  = dot_eb / den;
    const float ptx = st*ex, pty = st*ey, ptz = st*ez;
    const float o1  = sqrtf(ptx*ptx + pty*pty + ptz*ptz);
    const float ptl = fmaxf(o1, 1e-12f);
    const float n1tx = ptx/ptl, n1ty = pty/ptl, n1tz = ptz/ptl;
    const float ux =  p2[((size_t)b*64 + n)*3 + 0];
    const float uy = -p2[((size_t)b*64 + n)*3 + 1];
    const float uz = -p2[((size_t)b*64 + n)*3 + 2];
    const float o2 = sqrtf(ux*ux + uy*uy + uz*uz);
    const float ul = fmaxf(o2, 1e-12f);

    __shared__ float S[64][4];
    S[n][0] = ux/ul; S[n][1] = uy/ul; S[n][2] = uz/ul; S[n][3] = o2;
    __syncthreads();

    const float RAD2DEG = 57.295779513082323f;
    for (int m = 0; m < 64; ++m) {
        const float nx = S[m][0], ny = S[m][1], nz = S[m][2], o2m = S[m][3];
        float cosr = n1rx*nx + n1ry*ny + n1rz*nz;
        cosr = fminf(fmaxf(cosr, -1.f), 1.f);
        const float ndist = acosf(cosr) * RAD2DEG;
        const float cost = n1tx*nx + n1ty*ny + n1tz*nz;
        float od = (cost < 0.f) ? fabsf(o1 + o2m) : fabsf(o1 - o2m);
        od = fminf(fmaxf(od, 1e-10f), 5.f);
        pen[((size_t)b*64 + n)*64 + m] = od * 2.f + ndist * 0.1f;
    }
}

// ---------------------------------------------------------------------------
// Z build (fp32 desc): Z[b,n,m] = d1.d2/16 - pen; borders = bin.
// ---------------------------------------------------------------------------
__global__ __launch_bounds__(256)
void zbuild_kernel(const float* __restrict__ dfeat, const float* __restrict__ pen,
                   const float* __restrict__ binp, float* __restrict__ Z)
{
    const int b = blockIdx.x;
    const float* d1 = dfeat + (size_t)(b * 64) * 256;
    const float* d2 = dfeat + (size_t)(RM + b * 64) * 256;
    __shared__ float D1[64][65], D2[64][65];
    const int tid = threadIdx.x;
    const int txx = tid & 15, tyy = tid >> 4;
    float acc[4][4] = {{0.f,0.f,0.f,0.f},{0.f,0.f,0.f,0.f},
                       {0.f,0.f,0.f,0.f},{0.f,0.f,0.f,0.f}};
    for (int c0 = 0; c0 < 256; c0 += 64) {
        __syncthreads();
        for (int i = tid; i < 64 * 64; i += 256) {
            const int r = i >> 6, c = i & 63;
            D1[r][c] = d1[(size_t)r * 256 + c0 + c];
            D2[r][c] = d2[(size_t)r * 256 + c0 + c];
        }
        __syncthreads();
        for (int c = 0; c < 64; ++c) {
            const float a0 = D1[tyy*4+0][c], a1 = D1[tyy*4+1][c];
            const float a2 = D1[tyy*4+2][c], a3 = D1[tyy*4+3][c];
            const float b0 = D2[txx*4+0][c], b1 = D2[txx*4+1][c];
            const float b2 = D2[txx*4+2][c], b3 = D2[txx*4+3][c];
            acc[0][0] += a0*b0; acc[0][1] += a0*b1; acc[0][2] += a0*b2; acc[0][3] += a0*b3;
            acc[1][0] += a1*b0; acc[1][1] += a1*b1; acc[1][2] += a1*b2; acc[1][3] += a1*b3;
            acc[2][0] += a2*b0; acc[2][1] += a2*b1; acc[2][2] += a2*b2; acc[2][3] += a2*b3;
            acc[3][0] += a3*b0; acc[3][1] += a3*b1; acc[3][2] += a3*b2; acc[3][3] += a3*b3;
        }
    }
    const float bin = *binp;
    #pragma unroll
    for (int i = 0; i < 4; ++i)
        #pragma unroll
        for (int j = 0; j < 4; ++j) {
            const int n = tyy*4 + i, m = txx*4 + j;
            Z[(size_t)b*4225 + n*65 + m] =
                acc[i][j] * (1.f/16.f) - pen[((size_t)b*64 + n)*64 + m];
        }
    if (tid < 65) Z[(size_t)b*4225 + 64*65 + tid] = bin;
    if (tid < 64) Z[(size_t)b*4225 + tid*65 + 64] = bin;
}

// ---------------------------------------------------------------------------
// Sinkhorn, log2 domain, register-resident Z. Max-first reduce (9 exp2 per
// half-iter instead of 15). uu/vv padded to 72 (kills per-read index clamp).
// ---------------------------------------------------------------------------
__global__ __launch_bounds__(576)
void sinkhorn_kernel(const float* __restrict__ Zin, float* __restrict__ out)
{
    const int b = blockIdx.x;
    __shared__ float uu[72], vv[72];
    const int t  = threadIdx.x;
    const int rr = t >> 3, l8 = t & 7;
    const int act = (rr < 65);
    const float LOG2E = 1.4426950408889634f;
    const float LN2   = 0.69314718055994531f;

    float zrow[9], zcol[9];
    #pragma unroll
    for (int p = 0; p < 9; ++p) {
        const int j = l8 + p * 8;
        const int ok = act && (j < 65);
        zrow[p] = ok ? Zin[(size_t)b * 4225 + rr * 65 + j] * LOG2E : -3.0e38f;
        zcol[p] = ok ? Zin[(size_t)b * 4225 + j * 65 + rr] * LOG2E : -3.0e38f;
    }
    if (t < 72) { vv[t] = 0.f; uu[t] = 0.f; }   // pads stay 0 forever
    __syncthreads();

    const float mu2 = (rr < 64) ? -7.0f : -1.0f;

    for (int it = 0; it < 200; ++it) {
        {   // u update: lse2 over cols of row rr
            float vals[9];
            #pragma unroll
            for (int p = 0; p < 9; ++p) vals[p] = zrow[p] + vv[l8 + p * 8];
            float m = vals[0];
            #pragma unroll
            for (int p = 1; p < 9; ++p) m = fmaxf(m, vals[p]);
            #pragma unroll
            for (int o = 1; o < 8; o <<= 1) m = fmaxf(m, __shfl_xor(m, o));
            float sum = 0.f;
            #pragma unroll
            for (int p = 0; p < 9; ++p) sum += exp2f(vals[p] - m);
            #pragma unroll
            for (int o = 1; o < 8; o <<= 1) sum += __shfl_xor(sum, o);
            if (act && l8 == 0) uu[rr] = mu2 - (m + log2f(sum));
        }
        __syncthreads();
        {   // v update: lse2 over rows of col rr
            float vals[9];
            #pragma unroll
            for (int p = 0; p < 9; ++p) vals[p] = zcol[p] + uu[l8 + p * 8];
            float m = vals[0];
            #pragma unroll
            for (int p = 1; p < 9; ++p) m = fmaxf(m, vals[p]);
            #pragma unroll
            for (int o = 1; o < 8; o <<= 1) m = fmaxf(m, __shfl_xor(m, o));
            float sum = 0.f;
            #pragma unroll
            for (int p = 0; p < 9; ++p) sum += exp2f(vals[p] - m);
            #pragma unroll
            for (int o = 1; o < 8; o <<= 1) sum += __shfl_xor(sum, o);
            if (act && l8 == 0) vv[rr] = mu2 - (m + log2f(sum));
        }
        __syncthreads();
    }
    if (act) {
        const float ur = uu[rr];
        #pragma unroll
        for (int p = 0; p < 9; ++p) {
            const int j = l8 + p * 8;
            if (j < 65)
                out[(size_t)b * 4225 + rr * 65 + j] =
                    (zrow[p] + ur + vv[j] + 7.0f) * LN2;
        }
    }
}

// ---------------------------------------------------------------------------
extern "C" void kernel_launch(void* const* d_in, const int* in_sizes, int n_in,
                              void* d_out, int out_size, void* d_ws, size_t ws_size,
                              hipStream_t stream)
{
    const float* planeApp1 = (const float*)d_in[0];
    const float* planeApp2 = (const float*)d_in[1];
    const float* cam       = (const float*)d_in[2];
    const float* p1        = (const float*)d_in[3];
    const float* p2        = (const float*)d_in[4];
    const float* app_W     = (const float*)d_in[5];
    const float* app_b     = (const float*)d_in[6];
    const float* desc_W    = (const float*)d_in[7];
    const float* desc_b    = (const float*)d_in[8];
    const float* bin_score = (const float*)d_in[9];
    const float* Wq        = (const float*)d_in[10];
    const float* Wk        = (const float*)d_in[11];
    const float* Wv        = (const float*)d_in[12];
    const float* Wm        = (const float*)d_in[13];
    const float* W1        = (const float*)d_in[14];
    const float* W2        = (const float*)d_in[15];
    const float* ln1g      = (const float*)d_in[16];
    const float* ln1b      = (const float*)d_in[17];
    const float* ln2g      = (const float*)d_in[18];
    const float* ln2b      = (const float*)d_in[19];

    const size_t wq_elems   = (size_t)L_ * 768 * 256;
    const size_t wm_elems   = (size_t)L_ * 256 * 256;
    const size_t w1_elems   = (size_t)L_ * 512 * 512;
    const size_t w2_elems   = (size_t)L_ * 256 * 512;
    const size_t need = 5 * SZb * 2 + SZb * 4 + (size_t)B_ * 4096 * 4 +
        (wq_elems + wm_elems + w1_elems + w2_elems + 2 * 65536) * 2;
    if (ws_size < need) return;

    u16* Xb = (u16*)d_ws;
    u16* Qb = Xb + SZb;
    u16* Kb = Qb + SZb;
    u16* Vb = Kb + SZb;
    u16* Tb = Vb + SZb;
    float* Xf  = (float*)(Tb + SZb);
    float* pen = Xf + SZb;
    u16* wqkv = (u16*)(pen + (size_t)B_ * 4096);
    u16* wmt  = wqkv + wq_elems;
    u16* w1t  = wmt + wm_elems;
    u16* w2t  = w1t + w1_elems;
    u16* appt = w2t + w2_elems;
    u16* dsct = appt + 65536;
    float* outp = (float*)d_out;

    // ---- weight transpose+convert
    wtrans_kernel<<<dim3(4, 4, L_), 256, 0, stream>>>(Wq, wqkv, 256, 256, 65536, 768*256, 0,   256);
    wtrans_kernel<<<dim3(4, 4, L_), 256, 0, stream>>>(Wk, wqkv, 256, 256, 65536, 768*256, 256, 256);
    wtrans_kernel<<<dim3(4, 4, L_), 256, 0, stream>>>(Wv, wqkv, 256, 256, 65536, 768*256, 512, 256);
    wtrans_kernel<<<dim3(4, 4, L_), 256, 0, stream>>>(Wm, wmt,  256, 256, 65536, 65536,   0,   256);
    wtrans_kernel<<<dim3(8, 8, L_), 256, 0, stream>>>(W1, w1t,  512, 512, 262144, 262144, 0,   512);
    wtrans_kernel<<<dim3(8, 4, L_), 256, 0, stream>>>(W2, w2t,  512, 256, 131072, 131072, 0,   512);
    wtrans_kernel<<<dim3(4, 4, 1),  256, 0, stream>>>(app_W,  appt, 256, 256, 65536, 65536, 0, 256);
    wtrans_kernel<<<dim3(4, 4, 1),  256, 0, stream>>>(desc_W, dsct, 256, 256, 65536, 65536, 0, 256);

    cvt_kernel<<<(RM * D_ / 4 + 255) / 256, 256, 0, stream>>>(planeApp1, Qb, RM * D_ / 4);
    cvt_kernel<<<(RM * D_ / 4 + 255) / 256, 256, 0, stream>>>(planeApp2, Qb + (size_t)RM * D_, RM * D_ / 4);

    geom_kernel<<<B_, 64, 0, stream>>>(cam, p1, p2, pen);

    // x0 = planeApp @ app_W + app_b  -> Xf + Xb
    mgemm<256,0,0,1,1,1><<<dim3(RM2/128, 2), 256, 0, stream>>>(
        Qb, nullptr, appt, app_b, Xf, Xb, RM2, 256);

    for (int i = 0; i < L_; ++i) {
        const int selfl = (i % 2 == 0) ? 1 : 0;
        // fused QKV -> Qb|Kb|Vb
        mgemm<256,0,0,0,0,1><<<dim3(RM2/128, 6), 256, 0, stream>>>(
            Xb, nullptr, wqkv + (size_t)i*768*256, nullptr, nullptr, Qb, RM2, 256);
        // msg -> Qb (alias-safe)
        attn_kernel<<<2 * B_ * 8, 256, 0, stream>>>(Qb, Kb, Vb, Qb, selfl);
        // Wm + LN1 fused -> Tb (bf16)
        mgemm_ln<256,0><<<RM2/128, 512, 0, stream>>>(
            Qb, wmt + (size_t)i*65536, ln1g + i*256, ln1b + i*256,
            nullptr, Tb);
        // h = relu([Xb|Tb] @ W1) -> Qb..Kb region ([M,512] bf16)
        mgemm<512,1,1,0,0,1><<<dim3(RM2/128, 4), 256, 0, stream>>>(
            Xb, Tb, w1t + (size_t)i*262144, nullptr, nullptr, Qb, RM2, 512);
        // W2 + LN2 + residual fused: Xf += LN(h@W2), Xb = bf16(Xf)
        mgemm_ln<512,1><<<RM2/128, 512, 0, stream>>>(
            Qb, w2t + (size_t)i*131072, ln2g + i*256, ln2b + i*256,
            Xf, Xb);
    }

    // descriptors f32 -> Qb..Kb region
    mgemm<256,0,0,1,1,0><<<dim3(RM2/128, 2), 256, 0, stream>>>(
        Xb, nullptr, dsct, desc_b, (float*)Qb, nullptr, RM2, 256);

    zbuild_kernel<<<B_, 256, 0, stream>>>((float*)Qb, pen, bin_score, (float*)Vb);
    sinkhorn_kernel<<<B_, 576, 0, stream>>>((float*)Vb, outp);
}

// Round 8
// 2997.557 us; speedup vs baseline: 4.6132x; 1.0591x over previous
//
#include <hip/hip_runtime.h>
#include <math.h>
#include <stddef.h>
#include <stdint.h>

typedef unsigned short u16;
typedef unsigned int   u32;

static constexpr int B_   = 256;
static constexpr int N_   = 64;
static constexpr int D_   = 256;
static constexpr int L_   = 18;
static constexpr int RM   = B_ * N_;      // 16384 rows per stream
static constexpr int RM2  = 2 * RM;       // 32768 rows (both streams)
static constexpr size_t SZb = (size_t)RM2 * D_;   // 8,388,608 elements

typedef __attribute__((ext_vector_type(8))) short bf16x8;
typedef __attribute__((ext_vector_type(4))) float f32x4;

__device__ __forceinline__ float b2f(u16 u) {
    return __uint_as_float(((u32)u) << 16);
}
__device__ __forceinline__ u16 f2b(float f) {
    u32 x = __float_as_uint(f);
    return (u16)((x + 0x7FFFu + ((x >> 16) & 1u)) >> 16);
}
__device__ __forceinline__ void gl_lds16(const void* g, void* l) {
    __builtin_amdgcn_global_load_lds(
        (const __attribute__((address_space(1))) u32*)g,
        (__attribute__((address_space(3))) u32*)l, 16, 0, 0);
}

// ---------------------------------------------------------------------------
// bf16 MFMA GEMM, 2-phase double-buffered: stage(t+1) issued BEFORE compute(t),
// ONE __syncthreads per K-step. Tile 128x128, BK=64, 4 waves. Bt[N,K].
// ---------------------------------------------------------------------------
template<int K, int CONCAT, int RELU, int BIAS, int OUTF, int OUTB>
__global__ __launch_bounds__(256)
void mgemm(const u16* __restrict__ A1, const u16* __restrict__ A2,
           const u16* __restrict__ Bt, const float* __restrict__ bias,
           float* __restrict__ Cf, u16* __restrict__ Cb,
           int M, int splitn)
{
    constexpr int NT = K / 64;
    __shared__ u16 As[2][128 * 64];
    __shared__ u16 Bs[2][128 * 64];
    const int tid  = threadIdx.x;
    const int w    = tid >> 6;
    const int lane = tid & 63;
    const int wr   = w >> 1, wc = w & 1;
    const int row0 = blockIdx.x * 128;
    const int col0 = blockIdx.y * 128;
    const int lr   = lane & 15;
    const int lk   = (lane >> 4) * 8;
    const int srow = lane >> 3;
    const int schk = (lane & 7) * 8;

    auto stage = [&](int t, int buf) {
        const int k0 = t * 64;
        const u16* Aeff; int kloc, lda;
        if (CONCAT) {
            if (k0 < 256) { Aeff = A1; kloc = k0; } else { Aeff = A2; kloc = k0 - 256; }
            lda = 256;
        } else { Aeff = A1; kloc = k0; lda = K; }
        #pragma unroll
        for (int q = 0; q < 4; ++q) {
            const int i = w * 4 + q;
            gl_lds16(Aeff + (size_t)(row0 + i * 8 + srow) * lda + kloc + schk,
                     &As[buf][i * 512]);
            gl_lds16(Bt + (size_t)(col0 + i * 8 + srow) * K + t * 64 + schk,
                     &Bs[buf][i * 512]);
        }
    };

    f32x4 acc[4][4];
    #pragma unroll
    for (int m = 0; m < 4; ++m)
        #pragma unroll
        for (int n = 0; n < 4; ++n)
            acc[m][n] = (f32x4){0.f, 0.f, 0.f, 0.f};

    stage(0, 0);
    __syncthreads();
    #pragma unroll
    for (int t = 0; t < NT; ++t) {
        const int cur = t & 1;
        if (t + 1 < NT) stage(t + 1, cur ^ 1);
        #pragma unroll
        for (int kk = 0; kk < 2; ++kk) {
            bf16x8 af[4], bfr[4];
            #pragma unroll
            for (int m = 0; m < 4; ++m)
                af[m] = *(const bf16x8*)&As[cur][(wr * 64 + m * 16 + lr) * 64 + kk * 32 + lk];
            #pragma unroll
            for (int n = 0; n < 4; ++n)
                bfr[n] = *(const bf16x8*)&Bs[cur][(wc * 64 + n * 16 + lr) * 64 + kk * 32 + lk];
            #pragma unroll
            for (int m = 0; m < 4; ++m)
                #pragma unroll
                for (int n = 0; n < 4; ++n)
                    acc[m][n] = __builtin_amdgcn_mfma_f32_16x16x32_bf16(
                        af[m], bfr[n], acc[m][n], 0, 0, 0);
        }
        __syncthreads();
    }

    const size_t cbase = (size_t)(col0 / splitn) * (size_t)M * splitn;
    const int lc0 = col0 % splitn;
    #pragma unroll
    for (int m = 0; m < 4; ++m) {
        #pragma unroll
        for (int n = 0; n < 4; ++n) {
            const int gc = lc0 + wc * 64 + n * 16 + (lane & 15);
            #pragma unroll
            for (int r = 0; r < 4; ++r) {
                const int gr = row0 + wr * 64 + m * 16 + (lane >> 4) * 4 + r;
                float v = acc[m][n][r];
                if (BIAS) v += bias[gc];
                if (RELU) v = fmaxf(v, 0.f);
                const size_t idx = cbase + (size_t)gr * splitn + gc;
                if (OUTF) Cf[idx] = v;
                if (OUTB) Cb[idx] = f2b(v);
            }
        }
    }
}

// ---------------------------------------------------------------------------
// Fused GEMM + LayerNorm, 2-phase double-buffered. N = 256 (full rows
// in-block). BM=128, BK=64, 8 waves (2 row-halves x 4 col-groups).
// RES=0: outb = bf16(LN(acc)).  RES=1: outb = f2b(b2f(resb) + LN(acc)).
// ---------------------------------------------------------------------------
template<int K, int RES>
__global__ __launch_bounds__(512)
void mgemm_ln(const u16* __restrict__ A, const u16* __restrict__ Bt,
              const float* __restrict__ g, const float* __restrict__ beta,
              const u16* __restrict__ resb, u16* __restrict__ outb)
{
    constexpr int NT = K / 64;
    __shared__ u16 As[2][128 * 64];
    __shared__ u16 Bs[2][256 * 64];
    __shared__ float rs[4][128], rq[4][128];
    const int tid  = threadIdx.x;
    const int w    = tid >> 6;           // 0..7
    const int lane = tid & 63;
    const int wr   = w >> 2, wc = w & 3; // 2 x 4 wave grid
    const int row0 = blockIdx.x * 128;
    const int lr   = lane & 15;
    const int lk   = (lane >> 4) * 8;
    const int srow = lane >> 3;
    const int schk = (lane & 7) * 8;

    auto stage = [&](int t, int buf) {
        #pragma unroll
        for (int q = 0; q < 2; ++q) {
            const int i = w * 2 + q;
            gl_lds16(A + (size_t)(row0 + i * 8 + srow) * K + t * 64 + schk,
                     &As[buf][i * 512]);
        }
        #pragma unroll
        for (int q = 0; q < 4; ++q) {
            const int i = w * 4 + q;
            gl_lds16(Bt + (size_t)(i * 8 + srow) * K + t * 64 + schk,
                     &Bs[buf][i * 512]);
        }
    };

    f32x4 acc[4][4];
    #pragma unroll
    for (int m = 0; m < 4; ++m)
        #pragma unroll
        for (int n = 0; n < 4; ++n)
            acc[m][n] = (f32x4){0.f, 0.f, 0.f, 0.f};

    stage(0, 0);
    __syncthreads();
    #pragma unroll
    for (int t = 0; t < NT; ++t) {
        const int cur = t & 1;
        if (t + 1 < NT) stage(t + 1, cur ^ 1);
        #pragma unroll
        for (int kk = 0; kk < 2; ++kk) {
            bf16x8 af[4], bfr[4];
            #pragma unroll
            for (int m = 0; m < 4; ++m)
                af[m] = *(const bf16x8*)&As[cur][(wr * 64 + m * 16 + lr) * 64 + kk * 32 + lk];
            #pragma unroll
            for (int n = 0; n < 4; ++n)
                bfr[n] = *(const bf16x8*)&Bs[cur][(wc * 64 + n * 16 + lr) * 64 + kk * 32 + lk];
            #pragma unroll
            for (int m = 0; m < 4; ++m)
                #pragma unroll
                for (int n = 0; n < 4; ++n)
                    acc[m][n] = __builtin_amdgcn_mfma_f32_16x16x32_bf16(
                        af[m], bfr[n], acc[m][n], 0, 0, 0);
        }
        __syncthreads();
    }

    #pragma unroll
    for (int m = 0; m < 4; ++m) {
        #pragma unroll
        for (int r = 0; r < 4; ++r) {
            float s  = acc[m][0][r] + acc[m][1][r] + acc[m][2][r] + acc[m][3][r];
            float s2 = acc[m][0][r]*acc[m][0][r] + acc[m][1][r]*acc[m][1][r]
                     + acc[m][2][r]*acc[m][2][r] + acc[m][3][r]*acc[m][3][r];
            #pragma unroll
            for (int o = 1; o < 16; o <<= 1) {
                s  += __shfl_xor(s,  o);
                s2 += __shfl_xor(s2, o);
            }
            if ((lane & 15) == 0) {
                const int row = wr * 64 + m * 16 + (lane >> 4) * 4 + r;
                rs[wc][row] = s; rq[wc][row] = s2;
            }
        }
    }
    __syncthreads();
    if (tid < 128) {
        const float s = rs[0][tid] + rs[1][tid] + rs[2][tid] + rs[3][tid];
        const float q = rq[0][tid] + rq[1][tid] + rq[2][tid] + rq[3][tid];
        const float mean = s * (1.f / 256.f);
        const float var  = q * (1.f / 256.f) - mean * mean;
        rs[0][tid] = mean;
        rq[0][tid] = rsqrtf(var + 1e-5f);
    }
    __syncthreads();

    float gc[4], bc[4];
    #pragma unroll
    for (int n = 0; n < 4; ++n) {
        const int col = wc * 64 + n * 16 + lr;
        gc[n] = g[col]; bc[n] = beta[col];
    }
    #pragma unroll
    for (int m = 0; m < 4; ++m) {
        #pragma unroll
        for (int r = 0; r < 4; ++r) {
            const int row  = wr * 64 + m * 16 + (lane >> 4) * 4 + r;
            const float mean = rs[0][row], inv = rq[0][row];
            const int gr = row0 + row;
            #pragma unroll
            for (int n = 0; n < 4; ++n) {
                const int col = wc * 64 + n * 16 + lr;
                const size_t idx = (size_t)gr * 256 + col;
                float y = (acc[m][n][r] - mean) * inv * gc[n] + bc[n];
                if (RES) y += b2f(resb[idx]);
                outb[idx] = f2b(y);
            }
        }
    }
}

// ---------------------------------------------------------------------------
// Transpose+convert: W fp32 [K,N] (per layer) -> Wt bf16 [N,K].
// ---------------------------------------------------------------------------
__global__ __launch_bounds__(256)
void wtrans_kernel(const float* __restrict__ W, u16* __restrict__ Wt,
                   int K, int N, size_t in_lstride, size_t out_lstride,
                   int row_off, int ldk)
{
    __shared__ float T[64][65];
    const int k0 = blockIdx.x * 64, n0 = blockIdx.y * 64, l = blockIdx.z;
    const int t = threadIdx.x;
    const int r = t >> 2, c0 = (t & 3) * 16;
    const float* src = W + (size_t)l * in_lstride;
    #pragma unroll
    for (int q = 0; q < 4; ++q) {
        float4 v = *(const float4*)&src[(size_t)(k0 + r) * N + n0 + c0 + q * 4];
        T[r][c0 + q * 4 + 0] = v.x; T[r][c0 + q * 4 + 1] = v.y;
        T[r][c0 + q * 4 + 2] = v.z; T[r][c0 + q * 4 + 3] = v.w;
    }
    __syncthreads();
    u16 tmp[16];
    #pragma unroll
    for (int i = 0; i < 16; ++i) tmp[i] = f2b(T[c0 + i][r]);
    u16* dst = Wt + (size_t)l * out_lstride + (size_t)(row_off + n0 + r) * ldk + k0 + c0;
    *(uint4*)&dst[0] = *(const uint4*)&tmp[0];
    *(uint4*)&dst[8] = *(const uint4*)&tmp[8];
}

// elementwise fp32 -> bf16, two sources packed contiguously
__global__ __launch_bounds__(256)
void cvt2_kernel(const float* __restrict__ s1, const float* __restrict__ s2,
                 u16* __restrict__ dst, int n4half)
{
    int i = blockIdx.x * 256 + threadIdx.x;
    if (i >= 2 * n4half) return;
    const float* s = (i < n4half) ? s1 : s2;
    const int ii = (i < n4half) ? i : i - n4half;
    float4 v = *(const float4*)&s[(size_t)ii * 4];
    u16 o[4] = {f2b(v.x), f2b(v.y), f2b(v.z), f2b(v.w)};
    *(uint2*)&dst[(size_t)i * 4] = *(const uint2*)&o[0];
}

// ---------------------------------------------------------------------------
// Linear attention (bf16 in/out, fp32 compute). One block per (s,b,h).
// Mout may alias Q (Q fully staged to LDS before first sync).
// ---------------------------------------------------------------------------
__global__ __launch_bounds__(256)
void attn_kernel(const u16* __restrict__ Q, const u16* __restrict__ K,
                 const u16* __restrict__ V, u16* __restrict__ Mout, int selfl)
{
    const int bid = blockIdx.x;
    const int h = bid & 7;
    const int b = (bid >> 3) & 255;
    const int s = bid >> 11;
    const int ss = selfl ? s : (1 - s);
    const size_t qoff = ((size_t)(s  * RM) + b * N_) * D_ + h * 32;
    const size_t koff = ((size_t)(ss * RM) + b * N_) * D_ + h * 32;

    __shared__ float Ks[64][32];
    __shared__ float Vs[64][32];
    __shared__ float Qs[64][33];
    __shared__ float KV[32][32];
    __shared__ float Ksum[32];
    __shared__ float zden[64];

    const int t = threadIdx.x;
    {
        const int m = t >> 2, d0 = (t & 3) * 8;
        uint4 kq = *(const uint4*)&K[koff + (size_t)m * D_ + d0];
        uint4 vq = *(const uint4*)&V[koff + (size_t)m * D_ + d0];
        uint4 qq = *(const uint4*)&Q[qoff + (size_t)m * D_ + d0];
        const u16* kp = (const u16*)&kq;
        const u16* vp = (const u16*)&vq;
        const u16* qp = (const u16*)&qq;
        #pragma unroll
        for (int j = 0; j < 8; ++j) {
            float kx = b2f(kp[j]);
            Ks[m][d0 + j] = kx > 0.f ? kx + 1.f : __expf(kx);
            Vs[m][d0 + j] = b2f(vp[j]);
            float qx = b2f(qp[j]);
            Qs[m][d0 + j] = qx > 0.f ? qx + 1.f : __expf(qx);
        }
    }
    __syncthreads();
    if (t < 32) {
        float sacc = 0.f;
        for (int m = 0; m < 64; ++m) sacc += Ks[m][t];
        Ksum[t] = sacc;
    }
    for (int i = t; i < 32 * 32; i += 256) {
        const int d = i >> 5, e = i & 31;
        float acc = 0.f;
        for (int m = 0; m < 64; ++m) acc += Ks[m][d] * Vs[m][e];
        KV[d][e] = acc * (1.f / 64.f);
    }
    __syncthreads();
    if (t < 64) {
        float acc = 0.f;
        for (int d = 0; d < 32; ++d) acc += Qs[t][d] * Ksum[d];
        zden[t] = 1.f / (acc + 1e-6f);
    }
    __syncthreads();
    const int n = t >> 2, eg = t & 3;
    float acc[8] = {0.f,0.f,0.f,0.f,0.f,0.f,0.f,0.f};
    for (int d = 0; d < 32; ++d) {
        const float qv = Qs[n][d];
        #pragma unroll
        for (int j = 0; j < 8; ++j) acc[j] += qv * KV[d][eg * 8 + j];
    }
    const float zm = zden[n] * 64.f;
    u16 o[8];
    #pragma unroll
    for (int j = 0; j < 8; ++j) o[j] = f2b(acc[j] * zm);
    *(uint4*)&Mout[qoff + (size_t)n * D_ + eg * 8] = *(const uint4*)&o[0];
}

// ---------------------------------------------------------------------------
// Geometry penalty: pen = od*2 + ndist*0.1
// ---------------------------------------------------------------------------
__global__ __launch_bounds__(64)
void geom_kernel(const float* __restrict__ cam, const float* __restrict__ p1,
                 const float* __restrict__ p2, float* __restrict__ pen)
{
    const int b = blockIdx.x;
    const int n = threadIdx.x;

    const float tx = cam[b*7+0], ty = cam[b*7+1], tz = cam[b*7+2];
    float qw = cam[b*7+3], qx = cam[b*7+4], qy = cam[b*7+5], qz = cam[b*7+6];
    const float qn = rsqrtf(qw*qw + qx*qx + qy*qy + qz*qz);
    qw *= qn; qx *= qn; qy *= qn; qz *= qn;
    const float r00 = 1.f - 2.f*(qy*qy + qz*qz), r01 = 2.f*(qx*qy - qw*qz), r02 = 2.f*(qx*qz + qw*qy);
    const float r10 = 2.f*(qx*qy + qw*qz), r11 = 1.f - 2.f*(qx*qx + qz*qz), r12 = 2.f*(qy*qz - qw*qx);
    const float r20 = 2.f*(qx*qz - qw*qy), r21 = 2.f*(qy*qz + qw*qx), r22 = 1.f - 2.f*(qx*qx + qy*qy);

    const float px =  p1[((size_t)b*64 + n)*3 + 0];
    const float py = -p1[((size_t)b*64 + n)*3 + 1];
    const float pz = -p1[((size_t)b*64 + n)*3 + 2];
    const float ex = r00*px + r01*py + r02*pz;
    const float ey = r10*px + r11*py + r12*pz;
    const float ez = r20*px + r21*py + r22*pz;
    const float el2 = ex*ex + ey*ey + ez*ez;
    const float el  = sqrtf(el2);
    float den = el + 1e-5f; den = den * den;
    const float sr  = el2 / den;
    const float prx = sr*ex, pry = sr*ey, prz = sr*ez;
    const float prl = fmaxf(sqrtf(prx*prx + pry*pry + prz*prz), 1e-12f);
    const float n1rx = prx/prl, n1ry = pry/prl, n1rz = prz/prl;
    const float dot_eb = (ex+tx)*ex + (ey+ty)*ey + (ez+tz)*ez;
    const float st  = dot_eb / den;
    const float ptx = st*ex, pty = st*ey, ptz = st*ez;
    const float o1  = sqrtf(ptx*ptx + pty*pty + ptz*ptz);
    const float ptl = fmaxf(o1, 1e-12f);
    const float n1tx = ptx/ptl, n1ty = pty/ptl, n1tz = ptz/ptl;
    const float ux =  p2[((size_t)b*64 + n)*3 + 0];
    const float uy = -p2[((size_t)b*64 + n)*3 + 1];
    const float uz = -p2[((size_t)b*64 + n)*3 + 2];
    const float o2 = sqrtf(ux*ux + uy*uy + uz*uz);
    const float ul = fmaxf(o2, 1e-12f);

    __shared__ float S[64][4];
    S[n][0] = ux/ul; S[n][1] = uy/ul; S[n][2] = uz/ul; S[n][3] = o2;
    __syncthreads();

    const float RAD2DEG = 57.295779513082323f;
    for (int m = 0; m < 64; ++m) {
        const float nx = S[m][0], ny = S[m][1], nz = S[m][2], o2m = S[m][3];
        float cosr = n1rx*nx + n1ry*ny + n1rz*nz;
        cosr = fminf(fmaxf(cosr, -1.f), 1.f);
        const float ndist = acosf(cosr) * RAD2DEG;
        const float cost = n1tx*nx + n1ty*ny + n1tz*nz;
        float od = (cost < 0.f) ? fabsf(o1 + o2m) : fabsf(o1 - o2m);
        od = fminf(fmaxf(od, 1e-10f), 5.f);
        pen[((size_t)b*64 + n)*64 + m] = od * 2.f + ndist * 0.1f;
    }
}

// ---------------------------------------------------------------------------
// Z build (fp32 desc): Z[b,n,m] = d1.d2/16 - pen; borders = bin.
// ---------------------------------------------------------------------------
__global__ __launch_bounds__(256)
void zbuild_kernel(const float* __restrict__ dfeat, const float* __restrict__ pen,
                   const float* __restrict__ binp, float* __restrict__ Z)
{
    const int b = blockIdx.x;
    const float* d1 = dfeat + (size_t)(b * 64) * 256;
    const float* d2 = dfeat + (size_t)(RM + b * 64) * 256;
    __shared__ float D1[64][65], D2[64][65];
    const int tid = threadIdx.x;
    const int txx = tid & 15, tyy = tid >> 4;
    float acc[4][4] = {{0.f,0.f,0.f,0.f},{0.f,0.f,0.f,0.f},
                       {0.f,0.f,0.f,0.f},{0.f,0.f,0.f,0.f}};
    for (int c0 = 0; c0 < 256; c0 += 64) {
        __syncthreads();
        for (int i = tid; i < 64 * 64; i += 256) {
            const int r = i >> 6, c = i & 63;
            D1[r][c] = d1[(size_t)r * 256 + c0 + c];
            D2[r][c] = d2[(size_t)r * 256 + c0 + c];
        }
        __syncthreads();
        for (int c = 0; c < 64; ++c) {
            const float a0 = D1[tyy*4+0][c], a1 = D1[tyy*4+1][c];
            const float a2 = D1[tyy*4+2][c], a3 = D1[tyy*4+3][c];
            const float b0 = D2[txx*4+0][c], b1 = D2[txx*4+1][c];
            const float b2 = D2[txx*4+2][c], b3 = D2[txx*4+3][c];
            acc[0][0] += a0*b0; acc[0][1] += a0*b1; acc[0][2] += a0*b2; acc[0][3] += a0*b3;
            acc[1][0] += a1*b0; acc[1][1] += a1*b1; acc[1][2] += a1*b2; acc[1][3] += a1*b3;
            acc[2][0] += a2*b0; acc[2][1] += a2*b1; acc[2][2] += a2*b2; acc[2][3] += a2*b3;
            acc[3][0] += a3*b0; acc[3][1] += a3*b1; acc[3][2] += a3*b2; acc[3][3] += a3*b3;
        }
    }
    const float bin = *binp;
    #pragma unroll
    for (int i = 0; i < 4; ++i)
        #pragma unroll
        for (int j = 0; j < 4; ++j) {
            const int n = tyy*4 + i, m = txx*4 + j;
            Z[(size_t)b*4225 + n*65 + m] =
                acc[i][j] * (1.f/16.f) - pen[((size_t)b*64 + n)*64 + m];
        }
    if (tid < 65) Z[(size_t)b*4225 + 64*65 + tid] = bin;
    if (tid < 64) Z[(size_t)b*4225 + tid*65 + 64] = bin;
}

// ---------------------------------------------------------------------------
// Sinkhorn, log2 domain, register-resident Z with STATIC per-row/col max
// (safe: every row/col contains the bin entry, u/v bounded -> no flush of
// the whole sum, no overflow). Hot loop: add, exp2, tree-sum, 3 shfl, log2.
// ---------------------------------------------------------------------------
__global__ __launch_bounds__(576)
void sinkhorn_kernel(const float* __restrict__ Zin, float* __restrict__ out)
{
    const int b = blockIdx.x;
    __shared__ float uu[72], vv[72];
    const int t  = threadIdx.x;
    const int rr = t >> 3, l8 = t & 7;
    const int act = (rr < 65);
    const float LOG2E = 1.4426950408889634f;
    const float LN2   = 0.69314718055994531f;

    float zrow[9], zcol[9];
    #pragma unroll
    for (int p = 0; p < 9; ++p) {
        const int j = l8 + p * 8;
        const int ok = act && (j < 65);
        zrow[p] = ok ? Zin[(size_t)b * 4225 + rr * 65 + j] * LOG2E : -3.0e38f;
        zcol[p] = ok ? Zin[(size_t)b * 4225 + j * 65 + rr] * LOG2E : -3.0e38f;
    }
    // static maxes (computed once; Z constant over iterations)
    float mr = zrow[0], mc = zcol[0];
    #pragma unroll
    for (int p = 1; p < 9; ++p) { mr = fmaxf(mr, zrow[p]); mc = fmaxf(mc, zcol[p]); }
    #pragma unroll
    for (int o = 1; o < 8; o <<= 1) {
        mr = fmaxf(mr, __shfl_xor(mr, o));
        mc = fmaxf(mc, __shfl_xor(mc, o));
    }
    #pragma unroll
    for (int p = 0; p < 9; ++p) { zrow[p] -= mr; zcol[p] -= mc; }

    if (t < 72) { vv[t] = 0.f; uu[t] = 0.f; }
    __syncthreads();

    const float mu2 = (rr < 64) ? -7.0f : -1.0f;

    for (int it = 0; it < 200; ++it) {
        {   // u update
            float s0 = exp2f(zrow[0] + vv[l8]);
            float s1 = exp2f(zrow[1] + vv[l8 + 8]);
            float s2 = exp2f(zrow[2] + vv[l8 + 16]);
            float s3 = exp2f(zrow[3] + vv[l8 + 24]);
            s0 += exp2f(zrow[4] + vv[l8 + 32]);
            s1 += exp2f(zrow[5] + vv[l8 + 40]);
            s2 += exp2f(zrow[6] + vv[l8 + 48]);
            s3 += exp2f(zrow[7] + vv[l8 + 56]);
            s0 += exp2f(zrow[8] + vv[l8 + 64]);
            float sum = (s0 + s1) + (s2 + s3);
            #pragma unroll
            for (int o = 1; o < 8; o <<= 1) sum += __shfl_xor(sum, o);
            if (act && l8 == 0) uu[rr] = mu2 - mr - log2f(sum);
        }
        __syncthreads();
        {   // v update
            float s0 = exp2f(zcol[0] + uu[l8]);
            float s1 = exp2f(zcol[1] + uu[l8 + 8]);
            float s2 = exp2f(zcol[2] + uu[l8 + 16]);
            float s3 = exp2f(zcol[3] + uu[l8 + 24]);
            s0 += exp2f(zcol[4] + uu[l8 + 32]);
            s1 += exp2f(zcol[5] + uu[l8 + 40]);
            s2 += exp2f(zcol[6] + uu[l8 + 48]);
            s3 += exp2f(zcol[7] + uu[l8 + 56]);
            s0 += exp2f(zcol[8] + uu[l8 + 64]);
            float sum = (s0 + s1) + (s2 + s3);
            #pragma unroll
            for (int o = 1; o < 8; o <<= 1) sum += __shfl_xor(sum, o);
            if (act && l8 == 0) vv[rr] = mu2 - mc - log2f(sum);
        }
        __syncthreads();
    }
    if (act) {
        const float ur = uu[rr];
        #pragma unroll
        for (int p = 0; p < 9; ++p) {
            const int j = l8 + p * 8;
            if (j < 65)
                out[(size_t)b * 4225 + rr * 65 + j] =
                    (zrow[p] + mr + ur + vv[j] + 7.0f) * LN2;
        }
    }
}

// ---------------------------------------------------------------------------
extern "C" void kernel_launch(void* const* d_in, const int* in_sizes, int n_in,
                              void* d_out, int out_size, void* d_ws, size_t ws_size,
                              hipStream_t stream)
{
    const float* planeApp1 = (const float*)d_in[0];
    const float* planeApp2 = (const float*)d_in[1];
    const float* cam       = (const float*)d_in[2];
    const float* p1        = (const float*)d_in[3];
    const float* p2        = (const float*)d_in[4];
    const float* app_W     = (const float*)d_in[5];
    const float* app_b     = (const float*)d_in[6];
    const float* desc_W    = (const float*)d_in[7];
    const float* desc_b    = (const float*)d_in[8];
    const float* bin_score = (const float*)d_in[9];
    const float* Wq        = (const float*)d_in[10];
    const float* Wk        = (const float*)d_in[11];
    const float* Wv        = (const float*)d_in[12];
    const float* Wm        = (const float*)d_in[13];
    const float* W1        = (const float*)d_in[14];
    const float* W2        = (const float*)d_in[15];
    const float* ln1g      = (const float*)d_in[16];
    const float* ln1b      = (const float*)d_in[17];
    const float* ln2g      = (const float*)d_in[18];
    const float* ln2b      = (const float*)d_in[19];

    const size_t wq_elems   = (size_t)L_ * 768 * 256;
    const size_t wm_elems   = (size_t)L_ * 256 * 256;
    const size_t w1_elems   = (size_t)L_ * 512 * 512;
    const size_t w2_elems   = (size_t)L_ * 256 * 512;
    const size_t need = 5 * SZb * 2 + (size_t)B_ * 4096 * 4 +
        (wq_elems + wm_elems + w1_elems + w2_elems + 2 * 65536) * 2;
    if (ws_size < need) return;

    u16* Xb = (u16*)d_ws;
    u16* Qb = Xb + SZb;
    u16* Kb = Qb + SZb;
    u16* Vb = Kb + SZb;
    u16* Tb = Vb + SZb;
    float* pen = (float*)(Tb + SZb);
    u16* wqkv = (u16*)(pen + (size_t)B_ * 4096);
    u16* wmt  = wqkv + wq_elems;
    u16* w1t  = wmt + wm_elems;
    u16* w2t  = w1t + w1_elems;
    u16* appt = w2t + w2_elems;
    u16* dsct = appt + 65536;
    float* outp = (float*)d_out;

    // ---- weight transpose+convert
    wtrans_kernel<<<dim3(4, 4, L_), 256, 0, stream>>>(Wq, wqkv, 256, 256, 65536, 768*256, 0,   256);
    wtrans_kernel<<<dim3(4, 4, L_), 256, 0, stream>>>(Wk, wqkv, 256, 256, 65536, 768*256, 256, 256);
    wtrans_kernel<<<dim3(4, 4, L_), 256, 0, stream>>>(Wv, wqkv, 256, 256, 65536, 768*256, 512, 256);
    wtrans_kernel<<<dim3(4, 4, L_), 256, 0, stream>>>(Wm, wmt,  256, 256, 65536, 65536,   0,   256);
    wtrans_kernel<<<dim3(8, 8, L_), 256, 0, stream>>>(W1, w1t,  512, 512, 262144, 262144, 0,   512);
    wtrans_kernel<<<dim3(8, 4, L_), 256, 0, stream>>>(W2, w2t,  512, 256, 131072, 131072, 0,   512);
    wtrans_kernel<<<dim3(4, 4, 1),  256, 0, stream>>>(app_W,  appt, 256, 256, 65536, 65536, 0, 256);
    wtrans_kernel<<<dim3(4, 4, 1),  256, 0, stream>>>(desc_W, dsct, 256, 256, 65536, 65536, 0, 256);

    cvt2_kernel<<<(2 * (RM * D_ / 4) + 255) / 256, 256, 0, stream>>>(
        planeApp1, planeApp2, Qb, RM * D_ / 4);

    geom_kernel<<<B_, 64, 0, stream>>>(cam, p1, p2, pen);

    // x0 = planeApp @ app_W + app_b -> Xb (bf16 residual master)
    mgemm<256,0,0,1,0,1><<<dim3(RM2/128, 2), 256, 0, stream>>>(
        Qb, nullptr, appt, app_b, nullptr, Xb, RM2, 256);

    for (int i = 0; i < L_; ++i) {
        const int selfl = (i % 2 == 0) ? 1 : 0;
        // fused QKV -> Qb|Kb|Vb
        mgemm<256,0,0,0,0,1><<<dim3(RM2/128, 6), 256, 0, stream>>>(
            Xb, nullptr, wqkv + (size_t)i*768*256, nullptr, nullptr, Qb, RM2, 256);
        // msg -> Qb (alias-safe)
        attn_kernel<<<2 * B_ * 8, 256, 0, stream>>>(Qb, Kb, Vb, Qb, selfl);
        // Wm + LN1 fused -> Tb (bf16)
        mgemm_ln<256,0><<<RM2/128, 512, 0, stream>>>(
            Qb, wmt + (size_t)i*65536, ln1g + i*256, ln1b + i*256,
            nullptr, Tb);
        // h = relu([Xb|Tb] @ W1) -> Qb..Kb region ([M,512] bf16)
        mgemm<512,1,1,0,0,1><<<dim3(RM2/128, 4), 256, 0, stream>>>(
            Xb, Tb, w1t + (size_t)i*262144, nullptr, nullptr, Qb, RM2, 512);
        // W2 + LN2 + bf16 residual fused: Xb = f2b(b2f(Xb) + LN(h@W2))
        mgemm_ln<512,1><<<RM2/128, 512, 0, stream>>>(
            Qb, w2t + (size_t)i*131072, ln2g + i*256, ln2b + i*256,
            Xb, Xb);
    }

    // descriptors f32 -> Qb..Kb region
    mgemm<256,0,0,1,1,0><<<dim3(RM2/128, 2), 256, 0, stream>>>(
        Xb, nullptr, dsct, desc_b, (float*)Qb, nullptr, RM2, 256);

    zbuild_kernel<<<B_, 256, 0, stream>>>((float*)Qb, pen, bin_score, (float*)Vb);
    sinkhorn_kernel<<<B_, 576, 0, stream>>>((float*)Vb, outp);
}